// Round 10
// baseline (863.724 us; speedup 1.0000x reference)
//
#include <hip/hip_runtime.h>
#include <hip/hip_bf16.h>
#include <math.h>

constexpr int S_  = 4;
constexpr int MO  = 256;
constexpr int NO  = 128;
constexpr int FIN = 384;
#define CUTOFF_F 5.2f

typedef short bf16x8 __attribute__((ext_vector_type(8)));   // 8 bf16 = 4 VGPRs
typedef float f32x16 __attribute__((ext_vector_type(16)));  // 32x32 MFMA acc

__device__ __forceinline__ float gelu_tanh(float x) {
    float u = 0.7978845608028654f * (x + 0.044715f * x * x * x);
    return 0.5f * x * (1.0f + tanhf(u));
}
__device__ __forceinline__ unsigned short f2bf(float x) {   // RNE
    unsigned u = __float_as_uint(x);
    u = (u + 0x7fffu + ((u >> 16) & 1u)) >> 16;
    return (unsigned short)u;
}
__device__ __forceinline__ float bf2f(unsigned short h) {
    return __uint_as_float(((unsigned)h) << 16);
}

// ---------------- decay ----------------
__global__ void decay_kernel(const float* __restrict__ dist, const float* __restrict__ fa_,
                             const float* __restrict__ pf_, float* __restrict__ decay, int P) {
    int i = blockIdx.x * blockDim.x + threadIdx.x;
    if (i >= P) return;
    float fa = fa_[0], pf = pf_[0];
    float d = dist[i];
    float x = fminf(fmaxf(d / CUTOFF_F, 0.0f), 1.0f - 1e-6f);
    float f = expf(1.0f - 1.0f / (1.0f - x * x));
    float w = (d < CUTOFF_F) ? f : 0.0f;
    decay[i] = pf * pf * expf(-(fa * fa) * d) * w;
}

// ---------------- species sort: block-local hist + scan + fill ----------------
__global__ void species_hist(const int* __restrict__ sp, int* __restrict__ bhist, int N) {
    __shared__ int h[S_];
    int t = threadIdx.x, b = blockIdx.x;
    if (t < S_) h[t] = 0;
    __syncthreads();
    int i = b * 256 + t;
    if (i < N) {
        int s = sp[i];
        if (s >= 0 && s < S_) atomicAdd(&h[s], 1);   // LDS atomic
    }
    __syncthreads();
    if (t < S_) bhist[b * 4 + t] = h[t];
}
__global__ void species_scan(const int* __restrict__ bhist, int* __restrict__ cnt,
                             int* __restrict__ pbase, int nb) {
    if (threadIdx.x != 0) return;
    int tot[S_];
    for (int s = 0; s < S_; ++s) {
        int sum = 0;
        for (int b = 0; b < nb; ++b) sum += bhist[b * 4 + s];
        tot[s] = sum;
    }
    int off = 0;
    for (int s = 0; s < S_; ++s) { cnt[s] = tot[s]; cnt[4 + s] = off; off += tot[s]; }
    for (int s = 0; s < S_; ++s) {
        int run = cnt[4 + s];
        for (int b = 0; b < nb; ++b) { pbase[b * 4 + s] = run; run += bhist[b * 4 + s]; }
    }
}
__global__ void species_fill(const int* __restrict__ sp, const int* __restrict__ pbase,
                             int* __restrict__ perm, int N) {
    __shared__ int cur[S_];
    int t = threadIdx.x, b = blockIdx.x;
    if (t < S_) cur[t] = pbase[b * 4 + t];
    __syncthreads();
    int i = b * 256 + t;
    if (i < N) {
        int s = sp[i];
        if (s >= 0 && s < S_) {
            int pos = atomicAdd(&cur[s], 1);         // LDS atomic
            perm[pos] = i;
        }
    }
}

// ---------------- edge CSR build ----------------
__global__ void edge_count(const int* __restrict__ ai, int* __restrict__ degree, int P2) {
    int e = blockIdx.x * blockDim.x + threadIdx.x;
    if (e < P2) atomicAdd(&degree[ai[e]], 1);
}
__global__ void scan_rowptr(const int* __restrict__ degree, int* __restrict__ rowptr,
                            int* __restrict__ cursor, int N) {
    __shared__ int lds[1024];
    int t = threadIdx.x;
    int per = N / 1024;
    int base = t * per;
    int sum = 0;
    for (int i = 0; i < per; ++i) sum += degree[base + i];
    lds[t] = sum;
    __syncthreads();
    int v = sum;
    for (int ofs = 1; ofs < 1024; ofs <<= 1) {
        int add = (t >= ofs) ? lds[t - ofs] : 0;
        __syncthreads();
        v += add;
        lds[t] = v;
        __syncthreads();
    }
    int run = v - sum;   // exclusive prefix
    for (int i = 0; i < per; ++i) {
        int d = degree[base + i];
        rowptr[base + i] = run;
        cursor[base + i] = run;
        run += d;
    }
    if (t == 1023) rowptr[N] = run;
}
__global__ void edge_fill(const int* __restrict__ ai, const float* __restrict__ decay,
                          int* __restrict__ cursor, int* __restrict__ col,
                          float* __restrict__ wgt, int P) {
    int e = blockIdx.x * blockDim.x + threadIdx.x;
    if (e >= 2 * P) return;
    int p = (e < P) ? e : e - P;
    int dst = ai[e];
    int src = (e < P) ? ai[P + p] : ai[p];
    int pos = atomicAdd(&cursor[dst], 1);
    col[pos] = src;
    wgt[pos] = decay[p];
}

// ---------------- fp32 -> bf16 cast for aev ----------------
__global__ void cast_aev(const float* __restrict__ in, unsigned short* __restrict__ outb, int total4) {
    int i = blockIdx.x * blockDim.x + threadIdx.x;
    if (i >= total4) return;
    float4 v = ((const float4*)in)[i];
    ushort4 o; o.x = f2bf(v.x); o.y = f2bf(v.y); o.z = f2bf(v.z); o.w = f2bf(v.w);
    ((ushort4*)outb)[i] = o;
}

// ---------------- weight transpose+cast:  W [S][K][NC] fp32 -> Wt [S][NC][K] bf16 ----------------
__global__ void transpose_cast(const float* __restrict__ W, unsigned short* __restrict__ Wt,
                               int K, int NC) {
    __shared__ float tile[32][33];
    int s = blockIdx.z;
    int nb = blockIdx.x * 32, kb = blockIdx.y * 32;
    int tx = threadIdx.x & 31, ty = threadIdx.x >> 5;
    const float* Wb = W + (size_t)s * K * NC;
    unsigned short* Wo = Wt + (size_t)s * NC * K;
#pragma unroll
    for (int i = 0; i < 4; ++i) {
        int k = kb + ty + i * 8;
        tile[ty + i * 8][tx] = (k < K) ? Wb[(size_t)k * NC + nb + tx] : 0.0f;
    }
    __syncthreads();
#pragma unroll
    for (int i = 0; i < 4; ++i) {
        int n = nb + ty + i * 8;
        int k = kb + tx;
        if (k < K) Wo[(size_t)n * K + k] = f2bf(tile[tx][ty + i * 8]);
    }
}

// ---------------- species-routed bf16 MFMA GEMM: BK=64, double-buffered, 1 barrier/iter ----------------
// Tile 128x128, 4 waves (2x2), per-wave 64x64 via 2x2 frags of 32x32x16.
// Per K-step: stage A/B 64-k slab (8x16B loads/thread in flight), 16 MFMAs/wave.
constexpr int LSTR = 72;   // LDS row stride in shorts (144 B, 16B-aligned, 4-way read conflict)

template<int K, int NC, bool ACT>
__launch_bounds__(256, 2)
__global__ void mfma_gemm(const unsigned short* __restrict__ A, int lda,
                          const unsigned short* __restrict__ Wt,
                          const float* __restrict__ bias,
                          unsigned short* __restrict__ C, int ldc,
                          const int* __restrict__ cnt, const int* __restrict__ perm) {
    const int s = blockIdx.z;
    const int count = cnt[s];
    const int row0 = blockIdx.y * 128;
    if (row0 >= count) return;
    const int off = cnt[4 + s];
    const int c0 = blockIdx.x * 128;

    __shared__ unsigned short As[2][128 * LSTR];
    __shared__ unsigned short Bs[2][128 * LSTR];
    __shared__ int rix[128];

    const int t = threadIdx.x;
    const int lane = t & 63, wave = t >> 6;
    const int wm = wave >> 1, wn = wave & 1;
    const int l31 = lane & 31, lhi = lane >> 5;

    if (t < 128) {
        int ri = row0 + t;
        rix[t] = (ri < count) ? perm[off + ri] : -1;
    }
    __syncthreads();

    const int r2 = t >> 1, half = t & 1;        // 2 threads per row; each stages 32 k (64 B)
    const int gA = rix[r2];
    const unsigned short* Arow = (gA >= 0) ? (A + (size_t)gA * lda) : nullptr;
    const unsigned short* wrow = Wt + ((size_t)s * NC + c0 + r2) * K;

    f32x16 acc00 = {}, acc01 = {}, acc10 = {}, acc11 = {};

    uint4 pa[4], pb[4];
    auto prefetch = [&](int it) {
        const int kbase = it * 64 + half * 32;
#pragma unroll
        for (int q = 0; q < 4; ++q) {
            const int kk = kbase + q * 8;
            const bool v = (kk < K);           // K % 8 == 0 for all instantiations
            uint4 z = {0, 0, 0, 0};
            pa[q] = z; pb[q] = z;
            if (v) {
                if (Arow) pa[q] = *(const uint4*)(Arow + kk);
                pb[q] = *(const uint4*)(wrow + kk);
            }
        }
    };
    auto stage = [&](int buf) {
        const int base = r2 * LSTR + half * 32;
#pragma unroll
        for (int q = 0; q < 4; ++q) {
            *(uint4*)(&As[buf][base + q * 8]) = pa[q];
            *(uint4*)(&Bs[buf][base + q * 8]) = pb[q];
        }
    };

    const int NIT = (K + 63) / 64;
    prefetch(0);
    stage(0);
    int cur = 0;

    for (int it = 0; it < NIT; ++it) {
        __syncthreads();                       // stage(cur) visible; prior readers of cur^1 done
        const bool more = (it + 1 < NIT);
        if (more) prefetch(it + 1);            // issue loads; waited at stage() after MFMAs
#pragma unroll
        for (int ks = 0; ks < 4; ++ks) {
            const int ch = (ks * 2 + lhi) * 8;
            bf16x8 a0 = *(const bf16x8*)(&As[cur][(wm * 64 +  0 + l31) * LSTR + ch]);
            bf16x8 a1 = *(const bf16x8*)(&As[cur][(wm * 64 + 32 + l31) * LSTR + ch]);
            bf16x8 b0 = *(const bf16x8*)(&Bs[cur][(wn * 64 +  0 + l31) * LSTR + ch]);
            bf16x8 b1 = *(const bf16x8*)(&Bs[cur][(wn * 64 + 32 + l31) * LSTR + ch]);
            acc00 = __builtin_amdgcn_mfma_f32_32x32x16_bf16(a0, b0, acc00, 0, 0, 0);
            acc01 = __builtin_amdgcn_mfma_f32_32x32x16_bf16(a0, b1, acc01, 0, 0, 0);
            acc10 = __builtin_amdgcn_mfma_f32_32x32x16_bf16(a1, b0, acc10, 0, 0, 0);
            acc11 = __builtin_amdgcn_mfma_f32_32x32x16_bf16(a1, b1, acc11, 0, 0, 0);
        }
        if (more) stage(cur ^ 1);              // safe: cur^1 readers finished before barrier
        cur ^= 1;
    }

    const float* bp = bias + s * NC;
    auto store = [&](const f32x16& vv, int fm, int fn) {
        int col = c0 + wn * 64 + fn * 32 + l31;
        float bia = bp[col];
#pragma unroll
        for (int reg = 0; reg < 16; ++reg) {
            int frow = (reg & 3) + 8 * (reg >> 2) + 4 * lhi;   // verified C/D layout
            int r = wm * 64 + fm * 32 + frow;
            int g = rix[r];
            if (g >= 0) {
                float x = vv[reg] + bia;
                if (ACT) x = gelu_tanh(x);
                C[(size_t)g * ldc + col] = f2bf(x);
            }
        }
    };
    store(acc00, 0, 0); store(acc01, 0, 1); store(acc10, 1, 0); store(acc11, 1, 1);
}

// ---------------- CSR gather-reduce ----------------
template<int MODE>
__global__ void gather_rows(const unsigned short* __restrict__ neigh,
                            const int* __restrict__ rowptr, const int* __restrict__ col,
                            const float* __restrict__ wgt,
                            unsigned short* __restrict__ featout,
                            float* __restrict__ mergedout) {
    int row = blockIdx.x * 4 + (threadIdx.x >> 6);
    int lane = threadIdx.x & 63;
    int b = rowptr[row], e = rowptr[row + 1];
    int j = lane * 2;
    float a0 = 0.f, a1 = 0.f;
    for (int i = b; i < e; ++i) {
        int src = col[i];
        float w = wgt[i];
        unsigned pk = *(const unsigned*)(neigh + (size_t)src * NO + j);
        a0 += bf2f((unsigned short)(pk & 0xffffu)) * w;
        a1 += bf2f((unsigned short)(pk >> 16)) * w;
    }
    if (MODE == 0) {
        unsigned short o0 = f2bf(a0), o1 = f2bf(a1);
        *(unsigned*)(featout + (size_t)row * FIN + MO + j) = ((unsigned)o1 << 16) | (unsigned)o0;
    } else {
        float2 o; o.x = a0; o.y = a1;
        *(float2*)(mergedout + (size_t)row * NO + j) = o;
    }
}

// ---------------- final head ----------------
__global__ void final_kernel(const unsigned short* __restrict__ int1, const float* __restrict__ merged,
                             const float* __restrict__ Wf, const float* __restrict__ bfb,
                             const int* __restrict__ species, float* __restrict__ out, int N) {
    int w = (int)((blockIdx.x * (size_t)blockDim.x + threadIdx.x) >> 6);
    int lane = threadIdx.x & 63;
    if (w >= N) return;
    int s = species[w];
    float acc = 0.0f;
    if (s >= 0) {
        const float* wp = Wf + (size_t)s * FIN;
        for (int k = lane; k < MO; k += 64) acc += bf2f(int1[(size_t)w * MO + k]) * wp[k];
        for (int k = lane; k < NO; k += 64) acc += merged[(size_t)w * NO + k] * wp[MO + k];
    }
    for (int o = 32; o > 0; o >>= 1) acc += __shfl_down(acc, o, 64);
    if (lane == 0) {
        float pre = (s >= 0) ? (acc + bfb[s]) : 0.0f;
        out[2 * (size_t)N + w] = pre;
        out[w] = (float)s;
    }
}

// ---------------- per-batch charge correction ----------------
__global__ void charges_kernel(const float* __restrict__ pre_buf, const int* __restrict__ species,
                               const float* __restrict__ tc, float* __restrict__ out, int N, int A) {
    int b = blockIdx.x;
    int a = threadIdx.x;
    int idx = b * A + a;
    float pre = pre_buf[idx];
    int sp = species[idx];
    bool mask = (sp != -1);
    float v = pre;
    int c = mask ? 1 : 0;
    for (int o = 32; o > 0; o >>= 1) {
        v += __shfl_down(v, o, 64);
        c += __shfl_down(c, o, 64);
    }
    __shared__ float ssum[2];
    __shared__ int scnt[2];
    int wid = threadIdx.x >> 6;
    if ((threadIdx.x & 63) == 0) { ssum[wid] = v; scnt[wid] = c; }
    __syncthreads();
    float total = ssum[0] + ssum[1];
    int nreal = scnt[0] + scnt[1];
    float ch = pre + (tc[b] - total) / (float)max(nreal, 1);
    out[(size_t)N + idx] = mask ? ch : 0.0f;
}

extern "C" void kernel_launch(void* const* d_in, const int* in_sizes, int n_in,
                              void* d_out, int out_size, void* d_ws, size_t ws_size,
                              hipStream_t stream) {
    const int*   species = (const int*)d_in[0];
    const float* aev     = (const float*)d_in[1];
    const int*   ai      = (const int*)d_in[2];
    const float* dist    = (const float*)d_in[3];
    const float* tc      = (const float*)d_in[4];
    const float* Wm0 = (const float*)d_in[5];  const float* bm0 = (const float*)d_in[6];
    const float* Wn0 = (const float*)d_in[7];  const float* bn0 = (const float*)d_in[8];
    const float* Wm1 = (const float*)d_in[9];  const float* bm1 = (const float*)d_in[10];
    const float* Wn1 = (const float*)d_in[11]; const float* bn1 = (const float*)d_in[12];
    const float* Wf  = (const float*)d_in[13]; const float* bf  = (const float*)d_in[14];
    const float* factor    = (const float*)d_in[15];
    const float* prefactor = (const float*)d_in[16];

    const int N   = in_sizes[0];
    const int AEV = in_sizes[1] / N;       // 1008
    const int P   = in_sizes[3];
    const int B   = in_sizes[4];
    const int A   = N / B;

    float* out = (float*)d_out;

    // ---- workspace layout ----
    char* base = (char*)d_ws;
    size_t o = 0;
    auto take = [&](size_t bytes) -> char* {
        o = (o + 255) & ~(size_t)255;
        char* p = base + o; o += bytes; return p;
    };
    unsigned short* feat1_bf = (unsigned short*)take((size_t)N * FIN * 2);
    unsigned short* int1_bf  = (unsigned short*)take((size_t)N * MO * 2);
    char* region             = take((size_t)N * AEV * 2);
    // region overlay:
    //   [0, 66MB)    aev_bf  (dead after GEMM1)
    //   [0, 8MB)     neigh_bf
    //   [8, 24MB)    merged_f
    //   [24, ~28.5)  CSR: rowptr/cursor/degree/col/wgt  (built after GEMM1)
    unsigned short* aev_bf   = (unsigned short*)region;
    unsigned short* neigh_bf = (unsigned short*)region;
    size_t roff = ((size_t)N * NO * 2 + 255) & ~(size_t)255;
    float* merged_f = (float*)(region + roff);
    roff += (size_t)N * NO * 4;
    roff = (roff + 255) & ~(size_t)255;
    int* rowptr = (int*)(region + roff);  roff += (size_t)(N + 1) * 4; roff = (roff + 255) & ~(size_t)255;
    int* cursor = (int*)(region + roff);  roff += (size_t)N * 4;       roff = (roff + 255) & ~(size_t)255;
    int* degree = (int*)(region + roff);  roff += (size_t)N * 4;       roff = (roff + 255) & ~(size_t)255;
    int* ecol   = (int*)(region + roff);  roff += (size_t)2 * P * 4;   roff = (roff + 255) & ~(size_t)255;
    float* ewgt = (float*)(region + roff);
    float* decay = (float*)take((size_t)P * 4);
    unsigned short* Wm0t = (unsigned short*)take((size_t)S_ * MO * AEV * 2);
    unsigned short* Wn0t = (unsigned short*)take((size_t)S_ * NO * MO * 2);
    unsigned short* Wm1t = (unsigned short*)take((size_t)S_ * MO * FIN * 2);
    unsigned short* Wn1t = (unsigned short*)take((size_t)S_ * NO * MO * 2);
    int* perm  = (int*)take((size_t)N * 4);
    int* cnt   = (int*)take(64);
    const int nb = (N + 255) / 256;
    int* bhist = (int*)take((size_t)nb * 4 * 4);
    int* pbase = (int*)take((size_t)nb * 4 * 4);

    // ---- species sort + decay + casts/transposes ----
    species_hist<<<nb, 256, 0, stream>>>(species, bhist, N);
    species_scan<<<1, 64, 0, stream>>>(bhist, cnt, pbase, nb);
    species_fill<<<nb, 256, 0, stream>>>(species, pbase, perm, N);
    decay_kernel<<<(P + 255) / 256, 256, 0, stream>>>(dist, factor, prefactor, decay, P);

    const int tot4 = N * (AEV / 4);
    cast_aev<<<(tot4 + 255) / 256, 256, 0, stream>>>(aev, aev_bf, tot4);
    transpose_cast<<<dim3(MO / 32, (AEV + 31) / 32, S_), 256, 0, stream>>>(Wm0, Wm0t, AEV, MO);
    transpose_cast<<<dim3(NO / 32, MO / 32, S_), 256, 0, stream>>>(Wn0, Wn0t, MO, NO);
    transpose_cast<<<dim3(MO / 32, FIN / 32, S_), 256, 0, stream>>>(Wm1, Wm1t, FIN, MO);
    transpose_cast<<<dim3(NO / 32, MO / 32, S_), 256, 0, stream>>>(Wn1, Wn1t, MO, NO);

    const int rb = (N + 127) / 128;

    // ---- pass 0: GEMM1 first (aev_bf dies), then CSR build in its memory ----
    mfma_gemm<1008, 256, true><<<dim3(2, rb, S_), 256, 0, stream>>>(
        aev_bf, AEV, Wm0t, bm0, feat1_bf, FIN, cnt, perm);

    hipMemsetAsync(degree, 0, (size_t)N * 4, stream);
    edge_count<<<(2 * P + 255) / 256, 256, 0, stream>>>(ai, degree, 2 * P);
    scan_rowptr<<<1, 1024, 0, stream>>>(degree, rowptr, cursor, N);
    edge_fill<<<(2 * P + 255) / 256, 256, 0, stream>>>(ai, decay, cursor, ecol, ewgt, P);

    mfma_gemm<256, 128, true><<<dim3(1, rb, S_), 256, 0, stream>>>(
        feat1_bf, FIN, Wn0t, bn0, neigh_bf, NO, cnt, perm);
    gather_rows<0><<<N / 4, 256, 0, stream>>>(neigh_bf, rowptr, ecol, ewgt, feat1_bf, nullptr);

    // ---- pass 1 ----
    mfma_gemm<384, 256, true><<<dim3(2, rb, S_), 256, 0, stream>>>(
        feat1_bf, FIN, Wm1t, bm1, int1_bf, MO, cnt, perm);
    mfma_gemm<256, 128, true><<<dim3(1, rb, S_), 256, 0, stream>>>(
        int1_bf, MO, Wn1t, bn1, neigh_bf, NO, cnt, perm);
    gather_rows<1><<<N / 4, 256, 0, stream>>>(neigh_bf, rowptr, ecol, ewgt, nullptr, merged_f);

    // ---- head + charges ----
    final_kernel<<<(N * 64 + 255) / 256, 256, 0, stream>>>(
        int1_bf, merged_f, Wf, bf, species, out, N);
    charges_kernel<<<B, A, 0, stream>>>(out + 2 * (size_t)N, species, tc, out, N, A);
}

// Round 11
// 673.521 us; speedup vs baseline: 1.2824x; 1.2824x over previous
//
#include <hip/hip_runtime.h>
#include <hip/hip_bf16.h>
#include <math.h>

constexpr int S_  = 4;
constexpr int MO  = 256;
constexpr int NO  = 128;
constexpr int FIN = 384;
#define CUTOFF_F 5.2f

typedef short bf16x8 __attribute__((ext_vector_type(8)));   // 8 bf16 = 4 VGPRs
typedef float f32x16 __attribute__((ext_vector_type(16)));  // 32x32 MFMA acc

__device__ __forceinline__ float gelu_tanh(float x) {
    float u = 0.7978845608028654f * (x + 0.044715f * x * x * x);
    return 0.5f * x * (1.0f + tanhf(u));
}
__device__ __forceinline__ unsigned short f2bf(float x) {   // RNE
    unsigned u = __float_as_uint(x);
    u = (u + 0x7fffu + ((u >> 16) & 1u)) >> 16;
    return (unsigned short)u;
}
__device__ __forceinline__ float bf2f(unsigned short h) {
    return __uint_as_float(((unsigned)h) << 16);
}

// ---------------- decay ----------------
__global__ void decay_kernel(const float* __restrict__ dist, const float* __restrict__ fa_,
                             const float* __restrict__ pf_, float* __restrict__ decay, int P) {
    int i = blockIdx.x * blockDim.x + threadIdx.x;
    if (i >= P) return;
    float fa = fa_[0], pf = pf_[0];
    float d = dist[i];
    float x = fminf(fmaxf(d / CUTOFF_F, 0.0f), 1.0f - 1e-6f);
    float f = expf(1.0f - 1.0f / (1.0f - x * x));
    float w = (d < CUTOFF_F) ? f : 0.0f;
    decay[i] = pf * pf * expf(-(fa * fa) * d) * w;
}

// ---------------- species sort: block-local hist + scan + fill ----------------
__global__ void species_hist(const int* __restrict__ sp, int* __restrict__ bhist, int N) {
    __shared__ int h[S_];
    int t = threadIdx.x, b = blockIdx.x;
    if (t < S_) h[t] = 0;
    __syncthreads();
    int i = b * 256 + t;
    if (i < N) {
        int s = sp[i];
        if (s >= 0 && s < S_) atomicAdd(&h[s], 1);   // LDS atomic
    }
    __syncthreads();
    if (t < S_) bhist[b * 4 + t] = h[t];
}
__global__ void species_scan(const int* __restrict__ bhist, int* __restrict__ cnt,
                             int* __restrict__ pbase, int nb) {
    if (threadIdx.x != 0) return;
    int tot[S_];
    for (int s = 0; s < S_; ++s) {
        int sum = 0;
        for (int b = 0; b < nb; ++b) sum += bhist[b * 4 + s];
        tot[s] = sum;
    }
    int off = 0;
    for (int s = 0; s < S_; ++s) { cnt[s] = tot[s]; cnt[4 + s] = off; off += tot[s]; }
    for (int s = 0; s < S_; ++s) {
        int run = cnt[4 + s];
        for (int b = 0; b < nb; ++b) { pbase[b * 4 + s] = run; run += bhist[b * 4 + s]; }
    }
}
__global__ void species_fill(const int* __restrict__ sp, const int* __restrict__ pbase,
                             int* __restrict__ perm, int N) {
    __shared__ int cur[S_];
    int t = threadIdx.x, b = blockIdx.x;
    if (t < S_) cur[t] = pbase[b * 4 + t];
    __syncthreads();
    int i = b * 256 + t;
    if (i < N) {
        int s = sp[i];
        if (s >= 0 && s < S_) {
            int pos = atomicAdd(&cur[s], 1);         // LDS atomic
            perm[pos] = i;
        }
    }
}

// ---------------- edge CSR build ----------------
__global__ void edge_count(const int* __restrict__ ai, int* __restrict__ degree, int P2) {
    int e = blockIdx.x * blockDim.x + threadIdx.x;
    if (e < P2) atomicAdd(&degree[ai[e]], 1);
}
__global__ void scan_rowptr(const int* __restrict__ degree, int* __restrict__ rowptr,
                            int* __restrict__ cursor, int N) {
    __shared__ int lds[1024];
    int t = threadIdx.x;
    int per = N / 1024;
    int base = t * per;
    int sum = 0;
    for (int i = 0; i < per; ++i) sum += degree[base + i];
    lds[t] = sum;
    __syncthreads();
    int v = sum;
    for (int ofs = 1; ofs < 1024; ofs <<= 1) {
        int add = (t >= ofs) ? lds[t - ofs] : 0;
        __syncthreads();
        v += add;
        lds[t] = v;
        __syncthreads();
    }
    int run = v - sum;   // exclusive prefix
    for (int i = 0; i < per; ++i) {
        int d = degree[base + i];
        rowptr[base + i] = run;
        cursor[base + i] = run;
        run += d;
    }
    if (t == 1023) rowptr[N] = run;
}
__global__ void edge_fill(const int* __restrict__ ai, const float* __restrict__ decay,
                          int* __restrict__ cursor, int* __restrict__ col,
                          float* __restrict__ wgt, int P) {
    int e = blockIdx.x * blockDim.x + threadIdx.x;
    if (e >= 2 * P) return;
    int p = (e < P) ? e : e - P;
    int dst = ai[e];
    int src = (e < P) ? ai[P + p] : ai[p];
    int pos = atomicAdd(&cursor[dst], 1);
    col[pos] = src;
    wgt[pos] = decay[p];
}

// ---------------- fp32 -> bf16 cast for aev ----------------
__global__ void cast_aev(const float* __restrict__ in, unsigned short* __restrict__ outb, int total4) {
    int i = blockIdx.x * blockDim.x + threadIdx.x;
    if (i >= total4) return;
    float4 v = ((const float4*)in)[i];
    ushort4 o; o.x = f2bf(v.x); o.y = f2bf(v.y); o.z = f2bf(v.z); o.w = f2bf(v.w);
    ((ushort4*)outb)[i] = o;
}

// ---------------- weight transpose+cast:  W [S][K][NC] fp32 -> Wt [S][NC][K] bf16 ----------------
__global__ void transpose_cast(const float* __restrict__ W, unsigned short* __restrict__ Wt,
                               int K, int NC) {
    __shared__ float tile[32][33];
    int s = blockIdx.z;
    int nb = blockIdx.x * 32, kb = blockIdx.y * 32;
    int tx = threadIdx.x & 31, ty = threadIdx.x >> 5;
    const float* Wb = W + (size_t)s * K * NC;
    unsigned short* Wo = Wt + (size_t)s * NC * K;
#pragma unroll
    for (int i = 0; i < 4; ++i) {
        int k = kb + ty + i * 8;
        tile[ty + i * 8][tx] = (k < K) ? Wb[(size_t)k * NC + nb + tx] : 0.0f;
    }
    __syncthreads();
#pragma unroll
    for (int i = 0; i < 4; ++i) {
        int n = nb + ty + i * 8;
        int k = kb + tx;
        if (k < K) Wo[(size_t)n * K + k] = f2bf(tile[tx][ty + i * 8]);
    }
}

// ---------------- species-routed bf16 MFMA GEMM (r7-proven: single-buf BK=32, 20.5KB LDS) ----------------
// Tile 128x128, 4 waves (2x2), per-wave 64x64 via 2x2 frags of 32x32x16.
// Latency hiding comes from block co-residency (~7 blocks/CU), not intra-block dbuf.
template<int K, int NC, bool ACT>
__launch_bounds__(256, 2)
__global__ void mfma_gemm(const unsigned short* __restrict__ A, int lda,
                          const unsigned short* __restrict__ Wt,
                          const float* __restrict__ bias,
                          unsigned short* __restrict__ C, int ldc,
                          const int* __restrict__ cnt, const int* __restrict__ perm) {
    const int s = blockIdx.z;
    const int count = cnt[s];
    const int row0 = blockIdx.y * 128;
    if (row0 >= count) return;
    const int off = cnt[4 + s];
    const int c0 = blockIdx.x * 128;

    __shared__ unsigned short As[128 * 40];
    __shared__ unsigned short Bs[128 * 40];
    __shared__ int rix[128];

    const int t = threadIdx.x;
    const int lane = t & 63, wave = t >> 6;
    const int wm = wave >> 1, wn = wave & 1;
    const int l31 = lane & 31, lhi = lane >> 5;

    if (t < 128) {
        int ri = row0 + t;
        rix[t] = (ri < count) ? perm[off + ri] : -1;
    }
    __syncthreads();

    const int r2 = t >> 1, half = t & 1;
    const int gA = rix[r2];
    const unsigned short* wrow = Wt + ((size_t)s * NC + c0 + r2) * K;

    f32x16 acc00 = {}, acc01 = {}, acc10 = {}, acc11 = {};
    const uint4 z4 = {0, 0, 0, 0};

    for (int k0 = 0; k0 < K; k0 += 32) {
        const int kk = k0 + half * 16;
        const bool v = (kk < K);
        uint4 a0 = z4, a1 = z4, b0 = z4, b1 = z4;
        if (v) {
            if (gA >= 0) {
                const uint4* p = (const uint4*)(A + (size_t)gA * lda + kk);
                a0 = p[0]; a1 = p[1];
            }
            const uint4* q = (const uint4*)(wrow + kk);
            b0 = q[0]; b1 = q[1];
        }
        __syncthreads();
        *(uint4*)(&As[r2 * 40 + half * 16])     = a0;
        *(uint4*)(&As[r2 * 40 + half * 16 + 8]) = a1;
        *(uint4*)(&Bs[r2 * 40 + half * 16])     = b0;
        *(uint4*)(&Bs[r2 * 40 + half * 16 + 8]) = b1;
        __syncthreads();
#pragma unroll
        for (int ks = 0; ks < 2; ++ks) {
            const int ch = (ks * 2 + lhi) * 8;
            bf16x8 fa0 = *(const bf16x8*)(&As[(wm * 64 +  0 + l31) * 40 + ch]);
            bf16x8 fa1 = *(const bf16x8*)(&As[(wm * 64 + 32 + l31) * 40 + ch]);
            bf16x8 fb0 = *(const bf16x8*)(&Bs[(wn * 64 +  0 + l31) * 40 + ch]);
            bf16x8 fb1 = *(const bf16x8*)(&Bs[(wn * 64 + 32 + l31) * 40 + ch]);
            acc00 = __builtin_amdgcn_mfma_f32_32x32x16_bf16(fa0, fb0, acc00, 0, 0, 0);
            acc01 = __builtin_amdgcn_mfma_f32_32x32x16_bf16(fa0, fb1, acc01, 0, 0, 0);
            acc10 = __builtin_amdgcn_mfma_f32_32x32x16_bf16(fa1, fb0, acc10, 0, 0, 0);
            acc11 = __builtin_amdgcn_mfma_f32_32x32x16_bf16(fa1, fb1, acc11, 0, 0, 0);
        }
    }

    const float* bp = bias + s * NC;
    auto store = [&](const f32x16& vv, int fm, int fn) {
        int col = c0 + wn * 64 + fn * 32 + l31;
        float bia = bp[col];
#pragma unroll
        for (int reg = 0; reg < 16; ++reg) {
            int frow = (reg & 3) + 8 * (reg >> 2) + 4 * lhi;   // verified C/D layout
            int r = wm * 64 + fm * 32 + frow;
            int g = rix[r];
            if (g >= 0) {
                float x = vv[reg] + bia;
                if (ACT) x = gelu_tanh(x);
                C[(size_t)g * ldc + col] = f2bf(x);
            }
        }
    };
    store(acc00, 0, 0); store(acc01, 0, 1); store(acc10, 1, 0); store(acc11, 1, 1);
}

// ---------------- CSR gather-reduce, pass 0: bf16 into feat[:, MO:] (unroll x2) ----------------
__global__ void gather_rows0(const unsigned short* __restrict__ neigh,
                             const int* __restrict__ rowptr, const int* __restrict__ col,
                             const float* __restrict__ wgt,
                             unsigned short* __restrict__ featout) {
    int row = blockIdx.x * 4 + (threadIdx.x >> 6);
    int lane = threadIdx.x & 63;
    int b = rowptr[row], e = rowptr[row + 1];
    int j = lane * 2;
    float a0 = 0.f, a1 = 0.f, c0 = 0.f, c1 = 0.f;
    int i = b;
    for (; i + 1 < e; i += 2) {
        int s0 = col[i], s1 = col[i + 1];
        float w0 = wgt[i], w1 = wgt[i + 1];
        unsigned p0 = *(const unsigned*)(neigh + (size_t)s0 * NO + j);
        unsigned p1 = *(const unsigned*)(neigh + (size_t)s1 * NO + j);
        a0 += bf2f((unsigned short)(p0 & 0xffffu)) * w0;
        a1 += bf2f((unsigned short)(p0 >> 16)) * w0;
        c0 += bf2f((unsigned short)(p1 & 0xffffu)) * w1;
        c1 += bf2f((unsigned short)(p1 >> 16)) * w1;
    }
    if (i < e) {
        int s0 = col[i];
        float w0 = wgt[i];
        unsigned p0 = *(const unsigned*)(neigh + (size_t)s0 * NO + j);
        a0 += bf2f((unsigned short)(p0 & 0xffffu)) * w0;
        a1 += bf2f((unsigned short)(p0 >> 16)) * w0;
    }
    a0 += c0; a1 += c1;
    unsigned short o0 = f2bf(a0), o1 = f2bf(a1);
    *(unsigned*)(featout + (size_t)row * FIN + MO + j) = ((unsigned)o1 << 16) | (unsigned)o0;
}

// ---------------- fused pass-1 gather + final head ----------------
// One wave per atom: gather merged row in registers, dot with Wf[MO:], add int1 dot, reduce.
__global__ void gather_final(const unsigned short* __restrict__ neigh,
                             const int* __restrict__ rowptr, const int* __restrict__ col,
                             const float* __restrict__ wgt,
                             const unsigned short* __restrict__ int1,
                             const float* __restrict__ Wf, const float* __restrict__ bfb,
                             const int* __restrict__ species, float* __restrict__ out, int N) {
    int w = blockIdx.x * 4 + (threadIdx.x >> 6);
    int lane = threadIdx.x & 63;
    int s = species[w];
    float acc = 0.0f;
    if (s >= 0) {
        const float* wp = Wf + (size_t)s * FIN;
        // merged part: lane owns cols j, j+1
        int b = rowptr[w], e = rowptr[w + 1];
        int j = lane * 2;
        float a0 = 0.f, a1 = 0.f, c0 = 0.f, c1 = 0.f;
        int i = b;
        for (; i + 1 < e; i += 2) {
            int s0 = col[i], s1 = col[i + 1];
            float w0 = wgt[i], w1 = wgt[i + 1];
            unsigned p0 = *(const unsigned*)(neigh + (size_t)s0 * NO + j);
            unsigned p1 = *(const unsigned*)(neigh + (size_t)s1 * NO + j);
            a0 += bf2f((unsigned short)(p0 & 0xffffu)) * w0;
            a1 += bf2f((unsigned short)(p0 >> 16)) * w0;
            c0 += bf2f((unsigned short)(p1 & 0xffffu)) * w1;
            c1 += bf2f((unsigned short)(p1 >> 16)) * w1;
        }
        if (i < e) {
            int s0 = col[i];
            float w0 = wgt[i];
            unsigned p0 = *(const unsigned*)(neigh + (size_t)s0 * NO + j);
            a0 += bf2f((unsigned short)(p0 & 0xffffu)) * w0;
            a1 += bf2f((unsigned short)(p0 >> 16)) * w0;
        }
        a0 += c0; a1 += c1;
        acc = a0 * wp[MO + j] + a1 * wp[MO + j + 1];
        // int1 part: lane owns 4 contiguous cols
        const unsigned short* ip = int1 + (size_t)w * MO + lane * 4;
        ushort4 iv = *(const ushort4*)ip;
        const float* wq = wp + lane * 4;
        acc += bf2f(iv.x) * wq[0] + bf2f(iv.y) * wq[1] + bf2f(iv.z) * wq[2] + bf2f(iv.w) * wq[3];
    }
    for (int o = 32; o > 0; o >>= 1) acc += __shfl_down(acc, o, 64);
    if (lane == 0) {
        float pre = (s >= 0) ? (acc + bfb[s]) : 0.0f;
        out[2 * (size_t)N + w] = pre;
        out[w] = (float)s;
    }
}

// ---------------- per-batch charge correction ----------------
__global__ void charges_kernel(const float* __restrict__ pre_buf, const int* __restrict__ species,
                               const float* __restrict__ tc, float* __restrict__ out, int N, int A) {
    int b = blockIdx.x;
    int a = threadIdx.x;
    int idx = b * A + a;
    float pre = pre_buf[idx];
    int sp = species[idx];
    bool mask = (sp != -1);
    float v = pre;
    int c = mask ? 1 : 0;
    for (int o = 32; o > 0; o >>= 1) {
        v += __shfl_down(v, o, 64);
        c += __shfl_down(c, o, 64);
    }
    __shared__ float ssum[2];
    __shared__ int scnt[2];
    int wid = threadIdx.x >> 6;
    if ((threadIdx.x & 63) == 0) { ssum[wid] = v; scnt[wid] = c; }
    __syncthreads();
    float total = ssum[0] + ssum[1];
    int nreal = scnt[0] + scnt[1];
    float ch = pre + (tc[b] - total) / (float)max(nreal, 1);
    out[(size_t)N + idx] = mask ? ch : 0.0f;
}

extern "C" void kernel_launch(void* const* d_in, const int* in_sizes, int n_in,
                              void* d_out, int out_size, void* d_ws, size_t ws_size,
                              hipStream_t stream) {
    const int*   species = (const int*)d_in[0];
    const float* aev     = (const float*)d_in[1];
    const int*   ai      = (const int*)d_in[2];
    const float* dist    = (const float*)d_in[3];
    const float* tc      = (const float*)d_in[4];
    const float* Wm0 = (const float*)d_in[5];  const float* bm0 = (const float*)d_in[6];
    const float* Wn0 = (const float*)d_in[7];  const float* bn0 = (const float*)d_in[8];
    const float* Wm1 = (const float*)d_in[9];  const float* bm1 = (const float*)d_in[10];
    const float* Wn1 = (const float*)d_in[11]; const float* bn1 = (const float*)d_in[12];
    const float* Wf  = (const float*)d_in[13]; const float* bf  = (const float*)d_in[14];
    const float* factor    = (const float*)d_in[15];
    const float* prefactor = (const float*)d_in[16];

    const int N   = in_sizes[0];
    const int AEV = in_sizes[1] / N;       // 1008
    const int P   = in_sizes[3];
    const int B   = in_sizes[4];
    const int A   = N / B;

    float* out = (float*)d_out;

    // ---- workspace layout ----
    char* base = (char*)d_ws;
    size_t o = 0;
    auto take = [&](size_t bytes) -> char* {
        o = (o + 255) & ~(size_t)255;
        char* p = base + o; o += bytes; return p;
    };
    unsigned short* feat1_bf = (unsigned short*)take((size_t)N * FIN * 2);
    unsigned short* int1_bf  = (unsigned short*)take((size_t)N * MO * 2);
    char* region             = take((size_t)N * AEV * 2);
    // region overlay:
    //   [0, 66MB)    aev_bf  (dead after GEMM1)
    //   [0, 8MB)     neigh_bf
    //   [8, ~12.5MB) CSR: rowptr/cursor/degree/col/wgt  (built after GEMM1)
    unsigned short* aev_bf   = (unsigned short*)region;
    unsigned short* neigh_bf = (unsigned short*)region;
    size_t roff = ((size_t)N * NO * 2 + 255) & ~(size_t)255;
    int* rowptr = (int*)(region + roff);  roff += (size_t)(N + 1) * 4; roff = (roff + 255) & ~(size_t)255;
    int* cursor = (int*)(region + roff);  roff += (size_t)N * 4;       roff = (roff + 255) & ~(size_t)255;
    int* degree = (int*)(region + roff);  roff += (size_t)N * 4;       roff = (roff + 255) & ~(size_t)255;
    int* ecol   = (int*)(region + roff);  roff += (size_t)2 * P * 4;   roff = (roff + 255) & ~(size_t)255;
    float* ewgt = (float*)(region + roff);
    float* decay = (float*)take((size_t)P * 4);
    unsigned short* Wm0t = (unsigned short*)take((size_t)S_ * MO * AEV * 2);
    unsigned short* Wn0t = (unsigned short*)take((size_t)S_ * NO * MO * 2);
    unsigned short* Wm1t = (unsigned short*)take((size_t)S_ * MO * FIN * 2);
    unsigned short* Wn1t = (unsigned short*)take((size_t)S_ * NO * MO * 2);
    int* perm  = (int*)take((size_t)N * 4);
    int* cnt   = (int*)take(64);
    const int nb = (N + 255) / 256;
    int* bhist = (int*)take((size_t)nb * 4 * 4);
    int* pbase = (int*)take((size_t)nb * 4 * 4);

    // ---- species sort + decay + casts/transposes ----
    species_hist<<<nb, 256, 0, stream>>>(species, bhist, N);
    species_scan<<<1, 64, 0, stream>>>(bhist, cnt, pbase, nb);
    species_fill<<<nb, 256, 0, stream>>>(species, pbase, perm, N);
    decay_kernel<<<(P + 255) / 256, 256, 0, stream>>>(dist, factor, prefactor, decay, P);

    const int tot4 = N * (AEV / 4);
    cast_aev<<<(tot4 + 255) / 256, 256, 0, stream>>>(aev, aev_bf, tot4);
    transpose_cast<<<dim3(MO / 32, (AEV + 31) / 32, S_), 256, 0, stream>>>(Wm0, Wm0t, AEV, MO);
    transpose_cast<<<dim3(NO / 32, MO / 32, S_), 256, 0, stream>>>(Wn0, Wn0t, MO, NO);
    transpose_cast<<<dim3(MO / 32, FIN / 32, S_), 256, 0, stream>>>(Wm1, Wm1t, FIN, MO);
    transpose_cast<<<dim3(NO / 32, MO / 32, S_), 256, 0, stream>>>(Wn1, Wn1t, MO, NO);

    const int rb = (N + 127) / 128;

    // ---- pass 0: GEMM1 first (aev_bf dies), then CSR build in its memory ----
    mfma_gemm<1008, 256, true><<<dim3(2, rb, S_), 256, 0, stream>>>(
        aev_bf, AEV, Wm0t, bm0, feat1_bf, FIN, cnt, perm);

    hipMemsetAsync(degree, 0, (size_t)N * 4, stream);
    edge_count<<<(2 * P + 255) / 256, 256, 0, stream>>>(ai, degree, 2 * P);
    scan_rowptr<<<1, 1024, 0, stream>>>(degree, rowptr, cursor, N);
    edge_fill<<<(2 * P + 255) / 256, 256, 0, stream>>>(ai, decay, cursor, ecol, ewgt, P);

    mfma_gemm<256, 128, true><<<dim3(1, rb, S_), 256, 0, stream>>>(
        feat1_bf, FIN, Wn0t, bn0, neigh_bf, NO, cnt, perm);
    gather_rows0<<<N / 4, 256, 0, stream>>>(neigh_bf, rowptr, ecol, ewgt, feat1_bf);

    // ---- pass 1 ----
    mfma_gemm<384, 256, true><<<dim3(2, rb, S_), 256, 0, stream>>>(
        feat1_bf, FIN, Wm1t, bm1, int1_bf, MO, cnt, perm);
    mfma_gemm<256, 128, true><<<dim3(1, rb, S_), 256, 0, stream>>>(
        int1_bf, MO, Wn1t, bn1, neigh_bf, NO, cnt, perm);

    // ---- fused pass-1 gather + head, then charges ----
    gather_final<<<N / 4, 256, 0, stream>>>(
        neigh_bf, rowptr, ecol, ewgt, int1_bf, Wf, bf, species, out, N);
    charges_kernel<<<B, A, 0, stream>>>(out + 2 * (size_t)N, species, tc, out, N, A);
}

// Round 12
// 629.870 us; speedup vs baseline: 1.3713x; 1.0693x over previous
//
#include <hip/hip_runtime.h>
#include <hip/hip_bf16.h>
#include <math.h>

constexpr int S_  = 4;
constexpr int MO  = 256;
constexpr int NO  = 128;
constexpr int FIN = 384;
#define CUTOFF_F 5.2f

typedef short bf16x8 __attribute__((ext_vector_type(8)));   // 8 bf16 = 4 VGPRs
typedef float f32x16 __attribute__((ext_vector_type(16)));  // 32x32 MFMA acc

__device__ __forceinline__ float gelu_tanh(float x) {
    float u = 0.7978845608028654f * (x + 0.044715f * x * x * x);
    return 0.5f * x * (1.0f + tanhf(u));
}
__device__ __forceinline__ unsigned short f2bf(float x) {   // RNE
    unsigned u = __float_as_uint(x);
    u = (u + 0x7fffu + ((u >> 16) & 1u)) >> 16;
    return (unsigned short)u;
}
__device__ __forceinline__ float bf2f(unsigned short h) {
    return __uint_as_float(((unsigned)h) << 16);
}

// ---------------- decay ----------------
__global__ void decay_kernel(const float* __restrict__ dist, const float* __restrict__ fa_,
                             const float* __restrict__ pf_, float* __restrict__ decay, int P) {
    int i = blockIdx.x * blockDim.x + threadIdx.x;
    if (i >= P) return;
    float fa = fa_[0], pf = pf_[0];
    float d = dist[i];
    float x = fminf(fmaxf(d / CUTOFF_F, 0.0f), 1.0f - 1e-6f);
    float f = expf(1.0f - 1.0f / (1.0f - x * x));
    float w = (d < CUTOFF_F) ? f : 0.0f;
    decay[i] = pf * pf * expf(-(fa * fa) * d) * w;
}

// ---------------- species sort: block-local hist + scan + fill ----------------
__global__ void species_hist(const int* __restrict__ sp, int* __restrict__ bhist, int N) {
    __shared__ int h[S_];
    int t = threadIdx.x, b = blockIdx.x;
    if (t < S_) h[t] = 0;
    __syncthreads();
    int i = b * 256 + t;
    if (i < N) {
        int s = sp[i];
        if (s >= 0 && s < S_) atomicAdd(&h[s], 1);   // LDS atomic
    }
    __syncthreads();
    if (t < S_) bhist[b * 4 + t] = h[t];
}
__global__ void species_scan(const int* __restrict__ bhist, int* __restrict__ cnt,
                             int* __restrict__ pbase, int nb) {
    if (threadIdx.x != 0) return;
    int tot[S_];
    for (int s = 0; s < S_; ++s) {
        int sum = 0;
        for (int b = 0; b < nb; ++b) sum += bhist[b * 4 + s];
        tot[s] = sum;
    }
    int off = 0;
    for (int s = 0; s < S_; ++s) { cnt[s] = tot[s]; cnt[4 + s] = off; off += tot[s]; }
    for (int s = 0; s < S_; ++s) {
        int run = cnt[4 + s];
        for (int b = 0; b < nb; ++b) { pbase[b * 4 + s] = run; run += bhist[b * 4 + s]; }
    }
}
__global__ void species_fill(const int* __restrict__ sp, const int* __restrict__ pbase,
                             int* __restrict__ perm, int N) {
    __shared__ int cur[S_];
    int t = threadIdx.x, b = blockIdx.x;
    if (t < S_) cur[t] = pbase[b * 4 + t];
    __syncthreads();
    int i = b * 256 + t;
    if (i < N) {
        int s = sp[i];
        if (s >= 0 && s < S_) {
            int pos = atomicAdd(&cur[s], 1);         // LDS atomic
            perm[pos] = i;
        }
    }
}

// ---------------- edge CSR build ----------------
__global__ void edge_count(const int* __restrict__ ai, int* __restrict__ degree, int P2) {
    int e = blockIdx.x * blockDim.x + threadIdx.x;
    if (e < P2) atomicAdd(&degree[ai[e]], 1);
}
__global__ void scan_rowptr(const int* __restrict__ degree, int* __restrict__ rowptr,
                            int* __restrict__ cursor, int N) {
    __shared__ int lds[1024];
    int t = threadIdx.x;
    int per = N / 1024;
    int base = t * per;
    int sum = 0;
    for (int i = 0; i < per; ++i) sum += degree[base + i];
    lds[t] = sum;
    __syncthreads();
    int v = sum;
    for (int ofs = 1; ofs < 1024; ofs <<= 1) {
        int add = (t >= ofs) ? lds[t - ofs] : 0;
        __syncthreads();
        v += add;
        lds[t] = v;
        __syncthreads();
    }
    int run = v - sum;   // exclusive prefix
    for (int i = 0; i < per; ++i) {
        int d = degree[base + i];
        rowptr[base + i] = run;
        cursor[base + i] = run;
        run += d;
    }
    if (t == 1023) rowptr[N] = run;
}
__global__ void edge_fill(const int* __restrict__ ai, const float* __restrict__ decay,
                          int* __restrict__ cursor, int* __restrict__ col,
                          float* __restrict__ wgt, int P) {
    int e = blockIdx.x * blockDim.x + threadIdx.x;
    if (e >= 2 * P) return;
    int p = (e < P) ? e : e - P;
    int dst = ai[e];
    int src = (e < P) ? ai[P + p] : ai[p];
    int pos = atomicAdd(&cursor[dst], 1);
    col[pos] = src;
    wgt[pos] = decay[p];
}

// ---------------- fp32 -> bf16 cast for aev ----------------
__global__ void cast_aev(const float* __restrict__ in, unsigned short* __restrict__ outb, int total4) {
    int i = blockIdx.x * blockDim.x + threadIdx.x;
    if (i >= total4) return;
    float4 v = ((const float4*)in)[i];
    ushort4 o; o.x = f2bf(v.x); o.y = f2bf(v.y); o.z = f2bf(v.z); o.w = f2bf(v.w);
    ((ushort4*)outb)[i] = o;
}

// ---------------- weight transpose+cast:  W [S][K][NC] fp32 -> Wt [S][NC][K] bf16 ----------------
__global__ void transpose_cast(const float* __restrict__ W, unsigned short* __restrict__ Wt,
                               int K, int NC) {
    __shared__ float tile[32][33];
    int s = blockIdx.z;
    int nb = blockIdx.x * 32, kb = blockIdx.y * 32;
    int tx = threadIdx.x & 31, ty = threadIdx.x >> 5;
    const float* Wb = W + (size_t)s * K * NC;
    unsigned short* Wo = Wt + (size_t)s * NC * K;
#pragma unroll
    for (int i = 0; i < 4; ++i) {
        int k = kb + ty + i * 8;
        tile[ty + i * 8][tx] = (k < K) ? Wb[(size_t)k * NC + nb + tx] : 0.0f;
    }
    __syncthreads();
#pragma unroll
    for (int i = 0; i < 4; ++i) {
        int n = nb + ty + i * 8;
        int k = kb + tx;
        if (k < K) Wo[(size_t)n * K + k] = f2bf(tile[tx][ty + i * 8]);
    }
}

// ---------------- species-routed bf16 MFMA GEMM: 64x128 tile, 4 waves of 32x64 ----------------
// Grid-starvation fix: halving BM doubles working blocks (2 -> 4 waves/SIMD for GEMM1).
// Single-buffered BK=32 (r7-proven pipeline-free structure; TLP does the hiding).
template<int K, int NC, bool ACT>
__launch_bounds__(256, 2)
__global__ void mfma_gemm(const unsigned short* __restrict__ A, int lda,
                          const unsigned short* __restrict__ Wt,
                          const float* __restrict__ bias,
                          unsigned short* __restrict__ C, int ldc,
                          const int* __restrict__ cnt, const int* __restrict__ perm) {
    const int s = blockIdx.z;
    const int count = cnt[s];
    const int row0 = blockIdx.y * 64;
    if (row0 >= count) return;
    const int off = cnt[4 + s];
    const int c0 = blockIdx.x * 128;

    __shared__ unsigned short As[64 * 40];    // 5.1 KB
    __shared__ unsigned short Bs[128 * 40];   // 10.2 KB
    __shared__ int rix[64];

    const int t = threadIdx.x;
    const int lane = t & 63, wave = t >> 6;
    const int wm = wave >> 1, wn = wave & 1;      // wave covers rows wm*32, cols wn*64
    const int l31 = lane & 31, lhi = lane >> 5;

    if (t < 64) {
        int ri = row0 + t;
        rix[t] = (ri < count) ? perm[off + ri] : -1;
    }
    __syncthreads();

    const int ra = t >> 2, qa = t & 3;            // A staging: 4 thr/row, 16 B each
    const int rbr = t >> 1, hb = t & 1;           // B staging: 2 thr/row, 32 B each
    const int gA = rix[ra];
    const unsigned short* Arow = (gA >= 0) ? (A + (size_t)gA * lda) : nullptr;
    const unsigned short* wrow = Wt + ((size_t)s * NC + c0 + rbr) * K;

    f32x16 acc0 = {}, acc1 = {};
    const uint4 z4 = {0, 0, 0, 0};

    for (int k0 = 0; k0 < K; k0 += 32) {
        const int ka = k0 + qa * 8;
        uint4 av = z4;
        if (ka < K && Arow) av = *(const uint4*)(Arow + ka);   // K%8==0 all instantiations
        const int kb = k0 + hb * 16;
        uint4 b0 = z4, b1 = z4;
        if (kb < K) {
            const uint4* q = (const uint4*)(wrow + kb);
            b0 = q[0]; b1 = q[1];
        }
        __syncthreads();
        *(uint4*)(&As[ra * 40 + qa * 8]) = av;
        *(uint4*)(&Bs[rbr * 40 + hb * 16])     = b0;
        *(uint4*)(&Bs[rbr * 40 + hb * 16 + 8]) = b1;
        __syncthreads();
#pragma unroll
        for (int ks = 0; ks < 2; ++ks) {
            const int ch = (ks * 2 + lhi) * 8;
            bf16x8 fa  = *(const bf16x8*)(&As[(wm * 32 + l31) * 40 + ch]);
            bf16x8 fb0 = *(const bf16x8*)(&Bs[(wn * 64 +  0 + l31) * 40 + ch]);
            bf16x8 fb1 = *(const bf16x8*)(&Bs[(wn * 64 + 32 + l31) * 40 + ch]);
            acc0 = __builtin_amdgcn_mfma_f32_32x32x16_bf16(fa, fb0, acc0, 0, 0, 0);
            acc1 = __builtin_amdgcn_mfma_f32_32x32x16_bf16(fa, fb1, acc1, 0, 0, 0);
        }
    }

    const float* bp = bias + s * NC;
    auto store = [&](const f32x16& vv, int fn) {
        int col = c0 + wn * 64 + fn * 32 + l31;
        float bia = bp[col];
#pragma unroll
        for (int reg = 0; reg < 16; ++reg) {
            int frow = (reg & 3) + 8 * (reg >> 2) + 4 * lhi;   // verified C/D layout
            int r = wm * 32 + frow;
            int g = rix[r];
            if (g >= 0) {
                float x = vv[reg] + bia;
                if (ACT) x = gelu_tanh(x);
                C[(size_t)g * ldc + col] = f2bf(x);
            }
        }
    };
    store(acc0, 0); store(acc1, 1);
}

// ---------------- CSR gather-reduce, pass 0: bf16 into feat[:, MO:] (unroll x2) ----------------
__global__ void gather_rows0(const unsigned short* __restrict__ neigh,
                             const int* __restrict__ rowptr, const int* __restrict__ col,
                             const float* __restrict__ wgt,
                             unsigned short* __restrict__ featout) {
    int row = blockIdx.x * 4 + (threadIdx.x >> 6);
    int lane = threadIdx.x & 63;
    int b = rowptr[row], e = rowptr[row + 1];
    int j = lane * 2;
    float a0 = 0.f, a1 = 0.f, c0 = 0.f, c1 = 0.f;
    int i = b;
    for (; i + 1 < e; i += 2) {
        int s0 = col[i], s1 = col[i + 1];
        float w0 = wgt[i], w1 = wgt[i + 1];
        unsigned p0 = *(const unsigned*)(neigh + (size_t)s0 * NO + j);
        unsigned p1 = *(const unsigned*)(neigh + (size_t)s1 * NO + j);
        a0 += bf2f((unsigned short)(p0 & 0xffffu)) * w0;
        a1 += bf2f((unsigned short)(p0 >> 16)) * w0;
        c0 += bf2f((unsigned short)(p1 & 0xffffu)) * w1;
        c1 += bf2f((unsigned short)(p1 >> 16)) * w1;
    }
    if (i < e) {
        int s0 = col[i];
        float w0 = wgt[i];
        unsigned p0 = *(const unsigned*)(neigh + (size_t)s0 * NO + j);
        a0 += bf2f((unsigned short)(p0 & 0xffffu)) * w0;
        a1 += bf2f((unsigned short)(p0 >> 16)) * w0;
    }
    a0 += c0; a1 += c1;
    unsigned short o0 = f2bf(a0), o1 = f2bf(a1);
    *(unsigned*)(featout + (size_t)row * FIN + MO + j) = ((unsigned)o1 << 16) | (unsigned)o0;
}

// ---------------- fused pass-1 gather + final head ----------------
__global__ void gather_final(const unsigned short* __restrict__ neigh,
                             const int* __restrict__ rowptr, const int* __restrict__ col,
                             const float* __restrict__ wgt,
                             const unsigned short* __restrict__ int1,
                             const float* __restrict__ Wf, const float* __restrict__ bfb,
                             const int* __restrict__ species, float* __restrict__ out, int N) {
    int w = blockIdx.x * 4 + (threadIdx.x >> 6);
    int lane = threadIdx.x & 63;
    int s = species[w];
    float acc = 0.0f;
    if (s >= 0) {
        const float* wp = Wf + (size_t)s * FIN;
        int b = rowptr[w], e = rowptr[w + 1];
        int j = lane * 2;
        float a0 = 0.f, a1 = 0.f, c0 = 0.f, c1 = 0.f;
        int i = b;
        for (; i + 1 < e; i += 2) {
            int s0 = col[i], s1 = col[i + 1];
            float w0 = wgt[i], w1 = wgt[i + 1];
            unsigned p0 = *(const unsigned*)(neigh + (size_t)s0 * NO + j);
            unsigned p1 = *(const unsigned*)(neigh + (size_t)s1 * NO + j);
            a0 += bf2f((unsigned short)(p0 & 0xffffu)) * w0;
            a1 += bf2f((unsigned short)(p0 >> 16)) * w0;
            c0 += bf2f((unsigned short)(p1 & 0xffffu)) * w1;
            c1 += bf2f((unsigned short)(p1 >> 16)) * w1;
        }
        if (i < e) {
            int s0 = col[i];
            float w0 = wgt[i];
            unsigned p0 = *(const unsigned*)(neigh + (size_t)s0 * NO + j);
            a0 += bf2f((unsigned short)(p0 & 0xffffu)) * w0;
            a1 += bf2f((unsigned short)(p0 >> 16)) * w0;
        }
        a0 += c0; a1 += c1;
        acc = a0 * wp[MO + j] + a1 * wp[MO + j + 1];
        const unsigned short* ip = int1 + (size_t)w * MO + lane * 4;
        ushort4 iv = *(const ushort4*)ip;
        const float* wq = wp + lane * 4;
        acc += bf2f(iv.x) * wq[0] + bf2f(iv.y) * wq[1] + bf2f(iv.z) * wq[2] + bf2f(iv.w) * wq[3];
    }
    for (int o = 32; o > 0; o >>= 1) acc += __shfl_down(acc, o, 64);
    if (lane == 0) {
        float pre = (s >= 0) ? (acc + bfb[s]) : 0.0f;
        out[2 * (size_t)N + w] = pre;
        out[w] = (float)s;
    }
}

// ---------------- per-batch charge correction ----------------
__global__ void charges_kernel(const float* __restrict__ pre_buf, const int* __restrict__ species,
                               const float* __restrict__ tc, float* __restrict__ out, int N, int A) {
    int b = blockIdx.x;
    int a = threadIdx.x;
    int idx = b * A + a;
    float pre = pre_buf[idx];
    int sp = species[idx];
    bool mask = (sp != -1);
    float v = pre;
    int c = mask ? 1 : 0;
    for (int o = 32; o > 0; o >>= 1) {
        v += __shfl_down(v, o, 64);
        c += __shfl_down(c, o, 64);
    }
    __shared__ float ssum[2];
    __shared__ int scnt[2];
    int wid = threadIdx.x >> 6;
    if ((threadIdx.x & 63) == 0) { ssum[wid] = v; scnt[wid] = c; }
    __syncthreads();
    float total = ssum[0] + ssum[1];
    int nreal = scnt[0] + scnt[1];
    float ch = pre + (tc[b] - total) / (float)max(nreal, 1);
    out[(size_t)N + idx] = mask ? ch : 0.0f;
}

extern "C" void kernel_launch(void* const* d_in, const int* in_sizes, int n_in,
                              void* d_out, int out_size, void* d_ws, size_t ws_size,
                              hipStream_t stream) {
    const int*   species = (const int*)d_in[0];
    const float* aev     = (const float*)d_in[1];
    const int*   ai      = (const int*)d_in[2];
    const float* dist    = (const float*)d_in[3];
    const float* tc      = (const float*)d_in[4];
    const float* Wm0 = (const float*)d_in[5];  const float* bm0 = (const float*)d_in[6];
    const float* Wn0 = (const float*)d_in[7];  const float* bn0 = (const float*)d_in[8];
    const float* Wm1 = (const float*)d_in[9];  const float* bm1 = (const float*)d_in[10];
    const float* Wn1 = (const float*)d_in[11]; const float* bn1 = (const float*)d_in[12];
    const float* Wf  = (const float*)d_in[13]; const float* bf  = (const float*)d_in[14];
    const float* factor    = (const float*)d_in[15];
    const float* prefactor = (const float*)d_in[16];

    const int N   = in_sizes[0];
    const int AEV = in_sizes[1] / N;       // 1008
    const int P   = in_sizes[3];
    const int B   = in_sizes[4];
    const int A   = N / B;

    float* out = (float*)d_out;

    // ---- workspace layout ----
    char* base = (char*)d_ws;
    size_t o = 0;
    auto take = [&](size_t bytes) -> char* {
        o = (o + 255) & ~(size_t)255;
        char* p = base + o; o += bytes; return p;
    };
    unsigned short* feat1_bf = (unsigned short*)take((size_t)N * FIN * 2);
    unsigned short* int1_bf  = (unsigned short*)take((size_t)N * MO * 2);
    char* region             = take((size_t)N * AEV * 2);
    // region overlay:
    //   [0, 66MB)    aev_bf  (dead after GEMM1)
    //   [0, 8MB)     neigh_bf
    //   [8, ~12.5MB) CSR: rowptr/cursor/degree/col/wgt  (built after GEMM1)
    unsigned short* aev_bf   = (unsigned short*)region;
    unsigned short* neigh_bf = (unsigned short*)region;
    size_t roff = ((size_t)N * NO * 2 + 255) & ~(size_t)255;
    int* rowptr = (int*)(region + roff);  roff += (size_t)(N + 1) * 4; roff = (roff + 255) & ~(size_t)255;
    int* cursor = (int*)(region + roff);  roff += (size_t)N * 4;       roff = (roff + 255) & ~(size_t)255;
    int* degree = (int*)(region + roff);  roff += (size_t)N * 4;       roff = (roff + 255) & ~(size_t)255;
    int* ecol   = (int*)(region + roff);  roff += (size_t)2 * P * 4;   roff = (roff + 255) & ~(size_t)255;
    float* ewgt = (float*)(region + roff);
    float* decay = (float*)take((size_t)P * 4);
    unsigned short* Wm0t = (unsigned short*)take((size_t)S_ * MO * AEV * 2);
    unsigned short* Wn0t = (unsigned short*)take((size_t)S_ * NO * MO * 2);
    unsigned short* Wm1t = (unsigned short*)take((size_t)S_ * MO * FIN * 2);
    unsigned short* Wn1t = (unsigned short*)take((size_t)S_ * NO * MO * 2);
    int* perm  = (int*)take((size_t)N * 4);
    int* cnt   = (int*)take(64);
    const int nb = (N + 255) / 256;
    int* bhist = (int*)take((size_t)nb * 4 * 4);
    int* pbase = (int*)take((size_t)nb * 4 * 4);

    // ---- species sort + decay + casts/transposes ----
    species_hist<<<nb, 256, 0, stream>>>(species, bhist, N);
    species_scan<<<1, 64, 0, stream>>>(bhist, cnt, pbase, nb);
    species_fill<<<nb, 256, 0, stream>>>(species, pbase, perm, N);
    decay_kernel<<<(P + 255) / 256, 256, 0, stream>>>(dist, factor, prefactor, decay, P);

    const int tot4 = N * (AEV / 4);
    cast_aev<<<(tot4 + 255) / 256, 256, 0, stream>>>(aev, aev_bf, tot4);
    transpose_cast<<<dim3(MO / 32, (AEV + 31) / 32, S_), 256, 0, stream>>>(Wm0, Wm0t, AEV, MO);
    transpose_cast<<<dim3(NO / 32, MO / 32, S_), 256, 0, stream>>>(Wn0, Wn0t, MO, NO);
    transpose_cast<<<dim3(MO / 32, FIN / 32, S_), 256, 0, stream>>>(Wm1, Wm1t, FIN, MO);
    transpose_cast<<<dim3(NO / 32, MO / 32, S_), 256, 0, stream>>>(Wn1, Wn1t, MO, NO);

    const int rb = (N + 63) / 64;

    // ---- pass 0: GEMM1 first (aev_bf dies), then CSR build in its memory ----
    mfma_gemm<1008, 256, true><<<dim3(2, rb, S_), 256, 0, stream>>>(
        aev_bf, AEV, Wm0t, bm0, feat1_bf, FIN, cnt, perm);

    hipMemsetAsync(degree, 0, (size_t)N * 4, stream);
    edge_count<<<(2 * P + 255) / 256, 256, 0, stream>>>(ai, degree, 2 * P);
    scan_rowptr<<<1, 1024, 0, stream>>>(degree, rowptr, cursor, N);
    edge_fill<<<(2 * P + 255) / 256, 256, 0, stream>>>(ai, decay, cursor, ecol, ewgt, P);

    mfma_gemm<256, 128, true><<<dim3(1, rb, S_), 256, 0, stream>>>(
        feat1_bf, FIN, Wn0t, bn0, neigh_bf, NO, cnt, perm);
    gather_rows0<<<N / 4, 256, 0, stream>>>(neigh_bf, rowptr, ecol, ewgt, feat1_bf);

    // ---- pass 1 ----
    mfma_gemm<384, 256, true><<<dim3(2, rb, S_), 256, 0, stream>>>(
        feat1_bf, FIN, Wm1t, bm1, int1_bf, MO, cnt, perm);
    mfma_gemm<256, 128, true><<<dim3(1, rb, S_), 256, 0, stream>>>(
        int1_bf, MO, Wn1t, bn1, neigh_bf, NO, cnt, perm);

    // ---- fused pass-1 gather + head, then charges ----
    gather_final<<<N / 4, 256, 0, stream>>>(
        neigh_bf, rowptr, ecol, ewgt, int1_bf, Wf, bf, species, out, N);
    charges_kernel<<<B, A, 0, stream>>>(out + 2 * (size_t)N, species, tc, out, N, A);
}

// Round 13
// 610.931 us; speedup vs baseline: 1.4138x; 1.0310x over previous
//
#include <hip/hip_runtime.h>
#include <hip/hip_bf16.h>
#include <math.h>

constexpr int S_  = 4;
constexpr int MO  = 256;
constexpr int NO  = 128;
constexpr int FIN = 384;
#define CUTOFF_F 5.2f

typedef short bf16x8 __attribute__((ext_vector_type(8)));   // 8 bf16 = 4 VGPRs
typedef float f32x16 __attribute__((ext_vector_type(16)));  // 32x32 MFMA acc

__device__ __forceinline__ float gelu_tanh(float x) {
    float u = 0.7978845608028654f * (x + 0.044715f * x * x * x);
    return 0.5f * x * (1.0f + tanhf(u));
}
__device__ __forceinline__ unsigned short f2bf(float x) {   // RNE
    unsigned u = __float_as_uint(x);
    u = (u + 0x7fffu + ((u >> 16) & 1u)) >> 16;
    return (unsigned short)u;
}
__device__ __forceinline__ float bf2f(unsigned short h) {
    return __uint_as_float(((unsigned)h) << 16);
}
__device__ __forceinline__ float decay_of(float d, float fa, float pf) {
    float x = fminf(fmaxf(d / CUTOFF_F, 0.0f), 1.0f - 1e-6f);
    float f = expf(1.0f - 1.0f / (1.0f - x * x));
    float w = (d < CUTOFF_F) ? f : 0.0f;
    return pf * pf * expf(-(fa * fa) * d) * w;
}

// ---------------- species sort: block-local hist + scan + fill ----------------
__global__ void species_hist(const int* __restrict__ sp, int* __restrict__ bhist, int N) {
    __shared__ int h[S_];
    int t = threadIdx.x, b = blockIdx.x;
    if (t < S_) h[t] = 0;
    __syncthreads();
    int i = b * 256 + t;
    if (i < N) {
        int s = sp[i];
        if (s >= 0 && s < S_) atomicAdd(&h[s], 1);   // LDS atomic
    }
    __syncthreads();
    if (t < S_) bhist[b * 4 + t] = h[t];
}
__global__ void species_scan(const int* __restrict__ bhist, int* __restrict__ cnt,
                             int* __restrict__ pbase, int nb) {
    if (threadIdx.x != 0) return;
    int tot[S_];
    for (int s = 0; s < S_; ++s) {
        int sum = 0;
        for (int b = 0; b < nb; ++b) sum += bhist[b * 4 + s];
        tot[s] = sum;
    }
    int off = 0;
    for (int s = 0; s < S_; ++s) { cnt[s] = tot[s]; cnt[4 + s] = off; off += tot[s]; }
    for (int s = 0; s < S_; ++s) {
        int run = cnt[4 + s];
        for (int b = 0; b < nb; ++b) { pbase[b * 4 + s] = run; run += bhist[b * 4 + s]; }
    }
}
__global__ void species_fill(const int* __restrict__ sp, const int* __restrict__ pbase,
                             int* __restrict__ perm, int N) {
    __shared__ int cur[S_];
    int t = threadIdx.x, b = blockIdx.x;
    if (t < S_) cur[t] = pbase[b * 4 + t];
    __syncthreads();
    int i = b * 256 + t;
    if (i < N) {
        int s = sp[i];
        if (s >= 0 && s < S_) {
            int pos = atomicAdd(&cur[s], 1);         // LDS atomic
            perm[pos] = i;
        }
    }
}

// ---------------- edge CSR build (decay fused into fill) ----------------
__global__ void edge_count(const int* __restrict__ ai, int* __restrict__ degree, int P2) {
    int e = blockIdx.x * blockDim.x + threadIdx.x;
    if (e < P2) atomicAdd(&degree[ai[e]], 1);
}
__global__ void scan_rowptr(const int* __restrict__ degree, int* __restrict__ rowptr,
                            int* __restrict__ cursor, int N) {
    __shared__ int lds[1024];
    int t = threadIdx.x;
    int per = N / 1024;
    int base = t * per;
    int sum = 0;
    for (int i = 0; i < per; ++i) sum += degree[base + i];
    lds[t] = sum;
    __syncthreads();
    int v = sum;
    for (int ofs = 1; ofs < 1024; ofs <<= 1) {
        int add = (t >= ofs) ? lds[t - ofs] : 0;
        __syncthreads();
        v += add;
        lds[t] = v;
        __syncthreads();
    }
    int run = v - sum;   // exclusive prefix
    for (int i = 0; i < per; ++i) {
        int d = degree[base + i];
        rowptr[base + i] = run;
        cursor[base + i] = run;
        run += d;
    }
    if (t == 1023) rowptr[N] = run;
}
__global__ void edge_fill(const int* __restrict__ ai, const float* __restrict__ dist,
                          const float* __restrict__ fa_, const float* __restrict__ pf_,
                          int* __restrict__ cursor, int* __restrict__ col,
                          float* __restrict__ wgt, int P) {
    int e = blockIdx.x * blockDim.x + threadIdx.x;
    if (e >= 2 * P) return;
    int p = (e < P) ? e : e - P;
    int dst = ai[e];
    int src = (e < P) ? ai[P + p] : ai[p];
    int pos = atomicAdd(&cursor[dst], 1);
    col[pos] = src;
    wgt[pos] = decay_of(dist[p], fa_[0], pf_[0]);
}

// ---------------- fp32 -> bf16 cast for aev ----------------
__global__ void cast_aev(const float* __restrict__ in, unsigned short* __restrict__ outb, int total4) {
    int i = blockIdx.x * blockDim.x + threadIdx.x;
    if (i >= total4) return;
    float4 v = ((const float4*)in)[i];
    ushort4 o; o.x = f2bf(v.x); o.y = f2bf(v.y); o.z = f2bf(v.z); o.w = f2bf(v.w);
    ((ushort4*)outb)[i] = o;
}

// ---------------- weight transpose+cast:  W [S][K][NC] fp32 -> Wt [S][NC][K] bf16 ----------------
__global__ void transpose_cast(const float* __restrict__ W, unsigned short* __restrict__ Wt,
                               int K, int NC) {
    __shared__ float tile[32][33];
    int s = blockIdx.z;
    int nb = blockIdx.x * 32, kb = blockIdx.y * 32;
    int tx = threadIdx.x & 31, ty = threadIdx.x >> 5;
    const float* Wb = W + (size_t)s * K * NC;
    unsigned short* Wo = Wt + (size_t)s * NC * K;
#pragma unroll
    for (int i = 0; i < 4; ++i) {
        int k = kb + ty + i * 8;
        tile[ty + i * 8][tx] = (k < K) ? Wb[(size_t)k * NC + nb + tx] : 0.0f;
    }
    __syncthreads();
#pragma unroll
    for (int i = 0; i < 4; ++i) {
        int n = nb + ty + i * 8;
        int k = kb + tx;
        if (k < K) Wo[(size_t)n * K + k] = f2bf(tile[tx][ty + i * 8]);
    }
}

// ---------------- bf16 MFMA GEMM, 64x128 tile (4 waves of 32x64) — r12-proven ----------------
template<int K, int NC, bool ACT>
__launch_bounds__(256, 2)
__global__ void mfma_gemm(const unsigned short* __restrict__ A, int lda,
                          const unsigned short* __restrict__ Wt,
                          const float* __restrict__ bias,
                          unsigned short* __restrict__ C, int ldc,
                          const int* __restrict__ cnt, const int* __restrict__ perm) {
    const int s = blockIdx.z;
    const int count = cnt[s];
    const int row0 = blockIdx.y * 64;
    if (row0 >= count) return;
    const int off = cnt[4 + s];
    const int c0 = blockIdx.x * 128;

    __shared__ unsigned short As[64 * 40];
    __shared__ unsigned short Bs[128 * 40];
    __shared__ int rix[64];

    const int t = threadIdx.x;
    const int lane = t & 63, wave = t >> 6;
    const int wm = wave >> 1, wn = wave & 1;
    const int l31 = lane & 31, lhi = lane >> 5;

    if (t < 64) {
        int ri = row0 + t;
        rix[t] = (ri < count) ? perm[off + ri] : -1;
    }
    __syncthreads();

    const int ra = t >> 2, qa = t & 3;
    const int rbr = t >> 1, hb = t & 1;
    const int gA = rix[ra];
    const unsigned short* Arow = (gA >= 0) ? (A + (size_t)gA * lda) : nullptr;
    const unsigned short* wrow = Wt + ((size_t)s * NC + c0 + rbr) * K;

    f32x16 acc0 = {}, acc1 = {};
    const uint4 z4 = {0, 0, 0, 0};

    for (int k0 = 0; k0 < K; k0 += 32) {
        const int ka = k0 + qa * 8;
        uint4 av = z4;
        if (ka < K && Arow) av = *(const uint4*)(Arow + ka);
        const int kb = k0 + hb * 16;
        uint4 b0 = z4, b1 = z4;
        if (kb < K) {
            const uint4* q = (const uint4*)(wrow + kb);
            b0 = q[0]; b1 = q[1];
        }
        __syncthreads();
        *(uint4*)(&As[ra * 40 + qa * 8]) = av;
        *(uint4*)(&Bs[rbr * 40 + hb * 16])     = b0;
        *(uint4*)(&Bs[rbr * 40 + hb * 16 + 8]) = b1;
        __syncthreads();
#pragma unroll
        for (int ks = 0; ks < 2; ++ks) {
            const int ch = (ks * 2 + lhi) * 8;
            bf16x8 fa  = *(const bf16x8*)(&As[(wm * 32 + l31) * 40 + ch]);
            bf16x8 fb0 = *(const bf16x8*)(&Bs[(wn * 64 +  0 + l31) * 40 + ch]);
            bf16x8 fb1 = *(const bf16x8*)(&Bs[(wn * 64 + 32 + l31) * 40 + ch]);
            acc0 = __builtin_amdgcn_mfma_f32_32x32x16_bf16(fa, fb0, acc0, 0, 0, 0);
            acc1 = __builtin_amdgcn_mfma_f32_32x32x16_bf16(fa, fb1, acc1, 0, 0, 0);
        }
    }

    const float* bp = bias + s * NC;
    auto store = [&](const f32x16& vv, int fn) {
        int col = c0 + wn * 64 + fn * 32 + l31;
        float bia = bp[col];
#pragma unroll
        for (int reg = 0; reg < 16; ++reg) {
            int frow = (reg & 3) + 8 * (reg >> 2) + 4 * lhi;   // verified C/D layout
            int r = wm * 32 + frow;
            int g = rix[r];
            if (g >= 0) {
                float x = vv[reg] + bia;
                if (ACT) x = gelu_tanh(x);
                C[(size_t)g * ldc + col] = f2bf(x);
            }
        }
    };
    store(acc0, 0); store(acc1, 1);
}

// ---------------- bf16 MFMA GEMM, 32x128 tile (4 waves of 32x32) — for NC=128 TLP ----------------
template<int K, bool ACT>
__launch_bounds__(256, 2)
__global__ void mfma_gemm32(const unsigned short* __restrict__ A, int lda,
                            const unsigned short* __restrict__ Wt,
                            const float* __restrict__ bias,
                            unsigned short* __restrict__ C, int ldc,
                            const int* __restrict__ cnt, const int* __restrict__ perm) {
    const int s = blockIdx.z;
    const int count = cnt[s];
    const int row0 = blockIdx.y * 32;
    if (row0 >= count) return;
    const int off = cnt[4 + s];
    constexpr int NC = 128;

    __shared__ unsigned short As[32 * 40];    // 2.6 KB
    __shared__ unsigned short Bs[128 * 40];   // 10.2 KB
    __shared__ int rix[32];

    const int t = threadIdx.x;
    const int lane = t & 63, wave = t >> 6;   // wave covers cols wave*32
    const int l31 = lane & 31, lhi = lane >> 5;

    if (t < 32) {
        int ri = row0 + t;
        rix[t] = (ri < count) ? perm[off + ri] : -1;
    }
    __syncthreads();

    const int ra = t >> 3, qa = t & 7;        // A: 8 thr/row, 8 B (4 shorts) each
    const int rbr = t >> 1, hb = t & 1;       // B: 2 thr/row, 32 B each
    const int gA = rix[ra];
    const unsigned short* Arow = (gA >= 0) ? (A + (size_t)gA * lda) : nullptr;
    const unsigned short* wrow = Wt + ((size_t)s * NC + rbr) * K;

    f32x16 acc = {};
    const uint4 z4 = {0, 0, 0, 0};
    const uint2 z2 = {0, 0};

    for (int k0 = 0; k0 < K; k0 += 32) {
        const int ka = k0 + qa * 4;
        uint2 av = z2;
        if (ka < K && Arow) av = *(const uint2*)(Arow + ka);
        const int kb = k0 + hb * 16;
        uint4 b0 = z4, b1 = z4;
        if (kb < K) {
            const uint4* q = (const uint4*)(wrow + kb);
            b0 = q[0]; b1 = q[1];
        }
        __syncthreads();
        *(uint2*)(&As[ra * 40 + qa * 4]) = av;
        *(uint4*)(&Bs[rbr * 40 + hb * 16])     = b0;
        *(uint4*)(&Bs[rbr * 40 + hb * 16 + 8]) = b1;
        __syncthreads();
#pragma unroll
        for (int ks = 0; ks < 2; ++ks) {
            const int ch = (ks * 2 + lhi) * 8;
            bf16x8 fa = *(const bf16x8*)(&As[l31 * 40 + ch]);
            bf16x8 fb = *(const bf16x8*)(&Bs[(wave * 32 + l31) * 40 + ch]);
            acc = __builtin_amdgcn_mfma_f32_32x32x16_bf16(fa, fb, acc, 0, 0, 0);
        }
    }

    const float* bp = bias + s * NC;
    int col = wave * 32 + l31;
    float bia = bp[col];
#pragma unroll
    for (int reg = 0; reg < 16; ++reg) {
        int frow = (reg & 3) + 8 * (reg >> 2) + 4 * lhi;   // verified C/D layout
        int g = rix[frow];
        if (g >= 0) {
            float x = acc[reg] + bia;
            if (ACT) x = gelu_tanh(x);
            C[(size_t)g * ldc + col] = f2bf(x);
        }
    }
}

// ---------------- CSR gather-reduce, unroll x4, pass 0: bf16 into feat[:, MO:] ----------------
__global__ void gather_rows0(const unsigned short* __restrict__ neigh,
                             const int* __restrict__ rowptr, const int* __restrict__ col,
                             const float* __restrict__ wgt,
                             unsigned short* __restrict__ featout) {
    int row = blockIdx.x * 4 + (threadIdx.x >> 6);
    int lane = threadIdx.x & 63;
    int b = rowptr[row], e = rowptr[row + 1];
    int j = lane * 2;
    float a0 = 0.f, a1 = 0.f, c0 = 0.f, c1 = 0.f;
    int i = b;
    for (; i + 3 < e; i += 4) {
        int s0 = col[i], s1 = col[i + 1], s2 = col[i + 2], s3 = col[i + 3];
        float w0 = wgt[i], w1 = wgt[i + 1], w2 = wgt[i + 2], w3 = wgt[i + 3];
        unsigned p0 = *(const unsigned*)(neigh + (size_t)s0 * NO + j);
        unsigned p1 = *(const unsigned*)(neigh + (size_t)s1 * NO + j);
        unsigned p2 = *(const unsigned*)(neigh + (size_t)s2 * NO + j);
        unsigned p3 = *(const unsigned*)(neigh + (size_t)s3 * NO + j);
        a0 += bf2f((unsigned short)(p0 & 0xffffu)) * w0 + bf2f((unsigned short)(p2 & 0xffffu)) * w2;
        a1 += bf2f((unsigned short)(p0 >> 16)) * w0 + bf2f((unsigned short)(p2 >> 16)) * w2;
        c0 += bf2f((unsigned short)(p1 & 0xffffu)) * w1 + bf2f((unsigned short)(p3 & 0xffffu)) * w3;
        c1 += bf2f((unsigned short)(p1 >> 16)) * w1 + bf2f((unsigned short)(p3 >> 16)) * w3;
    }
    for (; i < e; ++i) {
        int s0 = col[i];
        float w0 = wgt[i];
        unsigned p0 = *(const unsigned*)(neigh + (size_t)s0 * NO + j);
        a0 += bf2f((unsigned short)(p0 & 0xffffu)) * w0;
        a1 += bf2f((unsigned short)(p0 >> 16)) * w0;
    }
    a0 += c0; a1 += c1;
    unsigned short o0 = f2bf(a0), o1 = f2bf(a1);
    *(unsigned*)(featout + (size_t)row * FIN + MO + j) = ((unsigned)o1 << 16) | (unsigned)o0;
}

// ---------------- fused pass-1 gather + final head (unroll x4) ----------------
__global__ void gather_final(const unsigned short* __restrict__ neigh,
                             const int* __restrict__ rowptr, const int* __restrict__ col,
                             const float* __restrict__ wgt,
                             const unsigned short* __restrict__ int1,
                             const float* __restrict__ Wf, const float* __restrict__ bfb,
                             const int* __restrict__ species, float* __restrict__ out, int N) {
    int w = blockIdx.x * 4 + (threadIdx.x >> 6);
    int lane = threadIdx.x & 63;
    int s = species[w];
    float acc = 0.0f;
    if (s >= 0) {
        const float* wp = Wf + (size_t)s * FIN;
        int b = rowptr[w], e = rowptr[w + 1];
        int j = lane * 2;
        float a0 = 0.f, a1 = 0.f, c0 = 0.f, c1 = 0.f;
        int i = b;
        for (; i + 3 < e; i += 4) {
            int s0 = col[i], s1 = col[i + 1], s2 = col[i + 2], s3 = col[i + 3];
            float w0 = wgt[i], w1 = wgt[i + 1], w2 = wgt[i + 2], w3 = wgt[i + 3];
            unsigned p0 = *(const unsigned*)(neigh + (size_t)s0 * NO + j);
            unsigned p1 = *(const unsigned*)(neigh + (size_t)s1 * NO + j);
            unsigned p2 = *(const unsigned*)(neigh + (size_t)s2 * NO + j);
            unsigned p3 = *(const unsigned*)(neigh + (size_t)s3 * NO + j);
            a0 += bf2f((unsigned short)(p0 & 0xffffu)) * w0 + bf2f((unsigned short)(p2 & 0xffffu)) * w2;
            a1 += bf2f((unsigned short)(p0 >> 16)) * w0 + bf2f((unsigned short)(p2 >> 16)) * w2;
            c0 += bf2f((unsigned short)(p1 & 0xffffu)) * w1 + bf2f((unsigned short)(p3 & 0xffffu)) * w3;
            c1 += bf2f((unsigned short)(p1 >> 16)) * w1 + bf2f((unsigned short)(p3 >> 16)) * w3;
        }
        for (; i < e; ++i) {
            int s0 = col[i];
            float w0 = wgt[i];
            unsigned p0 = *(const unsigned*)(neigh + (size_t)s0 * NO + j);
            a0 += bf2f((unsigned short)(p0 & 0xffffu)) * w0;
            a1 += bf2f((unsigned short)(p0 >> 16)) * w0;
        }
        a0 += c0; a1 += c1;
        acc = a0 * wp[MO + j] + a1 * wp[MO + j + 1];
        const unsigned short* ip = int1 + (size_t)w * MO + lane * 4;
        ushort4 iv = *(const ushort4*)ip;
        const float* wq = wp + lane * 4;
        acc += bf2f(iv.x) * wq[0] + bf2f(iv.y) * wq[1] + bf2f(iv.z) * wq[2] + bf2f(iv.w) * wq[3];
    }
    for (int o = 32; o > 0; o >>= 1) acc += __shfl_down(acc, o, 64);
    if (lane == 0) {
        float pre = (s >= 0) ? (acc + bfb[s]) : 0.0f;
        out[2 * (size_t)N + w] = pre;
        out[w] = (float)s;
    }
}

// ---------------- per-batch charge correction ----------------
__global__ void charges_kernel(const float* __restrict__ pre_buf, const int* __restrict__ species,
                               const float* __restrict__ tc, float* __restrict__ out, int N, int A) {
    int b = blockIdx.x;
    int a = threadIdx.x;
    int idx = b * A + a;
    float pre = pre_buf[idx];
    int sp = species[idx];
    bool mask = (sp != -1);
    float v = pre;
    int c = mask ? 1 : 0;
    for (int o = 32; o > 0; o >>= 1) {
        v += __shfl_down(v, o, 64);
        c += __shfl_down(c, o, 64);
    }
    __shared__ float ssum[2];
    __shared__ int scnt[2];
    int wid = threadIdx.x >> 6;
    if ((threadIdx.x & 63) == 0) { ssum[wid] = v; scnt[wid] = c; }
    __syncthreads();
    float total = ssum[0] + ssum[1];
    int nreal = scnt[0] + scnt[1];
    float ch = pre + (tc[b] - total) / (float)max(nreal, 1);
    out[(size_t)N + idx] = mask ? ch : 0.0f;
}

extern "C" void kernel_launch(void* const* d_in, const int* in_sizes, int n_in,
                              void* d_out, int out_size, void* d_ws, size_t ws_size,
                              hipStream_t stream) {
    const int*   species = (const int*)d_in[0];
    const float* aev     = (const float*)d_in[1];
    const int*   ai      = (const int*)d_in[2];
    const float* dist    = (const float*)d_in[3];
    const float* tc      = (const float*)d_in[4];
    const float* Wm0 = (const float*)d_in[5];  const float* bm0 = (const float*)d_in[6];
    const float* Wn0 = (const float*)d_in[7];  const float* bn0 = (const float*)d_in[8];
    const float* Wm1 = (const float*)d_in[9];  const float* bm1 = (const float*)d_in[10];
    const float* Wn1 = (const float*)d_in[11]; const float* bn1 = (const float*)d_in[12];
    const float* Wf  = (const float*)d_in[13]; const float* bf  = (const float*)d_in[14];
    const float* factor    = (const float*)d_in[15];
    const float* prefactor = (const float*)d_in[16];

    const int N   = in_sizes[0];
    const int AEV = in_sizes[1] / N;       // 1008
    const int P   = in_sizes[3];
    const int B   = in_sizes[4];
    const int A   = N / B;

    float* out = (float*)d_out;

    // ---- workspace layout ----
    char* base = (char*)d_ws;
    size_t o = 0;
    auto take = [&](size_t bytes) -> char* {
        o = (o + 255) & ~(size_t)255;
        char* p = base + o; o += bytes; return p;
    };
    unsigned short* feat1_bf = (unsigned short*)take((size_t)N * FIN * 2);
    unsigned short* int1_bf  = (unsigned short*)take((size_t)N * MO * 2);
    char* region             = take((size_t)N * AEV * 2);
    // region overlay:
    //   [0, 66MB)    aev_bf  (dead after GEMM1)
    //   [0, 8MB)     neigh_bf
    //   [8, ~12.5MB) CSR: rowptr/cursor/degree/col/wgt  (built after GEMM1)
    unsigned short* aev_bf   = (unsigned short*)region;
    unsigned short* neigh_bf = (unsigned short*)region;
    size_t roff = ((size_t)N * NO * 2 + 255) & ~(size_t)255;
    int* rowptr = (int*)(region + roff);  roff += (size_t)(N + 1) * 4; roff = (roff + 255) & ~(size_t)255;
    int* cursor = (int*)(region + roff);  roff += (size_t)N * 4;       roff = (roff + 255) & ~(size_t)255;
    int* degree = (int*)(region + roff);  roff += (size_t)N * 4;       roff = (roff + 255) & ~(size_t)255;
    int* ecol   = (int*)(region + roff);  roff += (size_t)2 * P * 4;   roff = (roff + 255) & ~(size_t)255;
    float* ewgt = (float*)(region + roff);
    unsigned short* Wm0t = (unsigned short*)take((size_t)S_ * MO * AEV * 2);
    unsigned short* Wn0t = (unsigned short*)take((size_t)S_ * NO * MO * 2);
    unsigned short* Wm1t = (unsigned short*)take((size_t)S_ * MO * FIN * 2);
    unsigned short* Wn1t = (unsigned short*)take((size_t)S_ * NO * MO * 2);
    int* perm  = (int*)take((size_t)N * 4);
    int* cnt   = (int*)take(64);
    const int nb = (N + 255) / 256;
    int* bhist = (int*)take((size_t)nb * 4 * 4);
    int* pbase = (int*)take((size_t)nb * 4 * 4);

    // ---- species sort + casts/transposes ----
    species_hist<<<nb, 256, 0, stream>>>(species, bhist, N);
    species_scan<<<1, 64, 0, stream>>>(bhist, cnt, pbase, nb);
    species_fill<<<nb, 256, 0, stream>>>(species, pbase, perm, N);

    const int tot4 = N * (AEV / 4);
    cast_aev<<<(tot4 + 255) / 256, 256, 0, stream>>>(aev, aev_bf, tot4);
    transpose_cast<<<dim3(MO / 32, (AEV + 31) / 32, S_), 256, 0, stream>>>(Wm0, Wm0t, AEV, MO);
    transpose_cast<<<dim3(NO / 32, MO / 32, S_), 256, 0, stream>>>(Wn0, Wn0t, MO, NO);
    transpose_cast<<<dim3(MO / 32, FIN / 32, S_), 256, 0, stream>>>(Wm1, Wm1t, FIN, MO);
    transpose_cast<<<dim3(NO / 32, MO / 32, S_), 256, 0, stream>>>(Wn1, Wn1t, MO, NO);

    const int rb  = (N + 63) / 64;
    const int rb32 = (N + 31) / 32;

    // ---- pass 0: GEMM1 first (aev_bf dies), then CSR build in its memory ----
    mfma_gemm<1008, 256, true><<<dim3(2, rb, S_), 256, 0, stream>>>(
        aev_bf, AEV, Wm0t, bm0, feat1_bf, FIN, cnt, perm);

    hipMemsetAsync(degree, 0, (size_t)N * 4, stream);
    edge_count<<<(2 * P + 255) / 256, 256, 0, stream>>>(ai, degree, 2 * P);
    scan_rowptr<<<1, 1024, 0, stream>>>(degree, rowptr, cursor, N);
    edge_fill<<<(2 * P + 255) / 256, 256, 0, stream>>>(ai, dist, factor, prefactor,
                                                       cursor, ecol, ewgt, P);

    mfma_gemm32<256, true><<<dim3(1, rb32, S_), 256, 0, stream>>>(
        feat1_bf, FIN, Wn0t, bn0, neigh_bf, NO, cnt, perm);
    gather_rows0<<<N / 4, 256, 0, stream>>>(neigh_bf, rowptr, ecol, ewgt, feat1_bf);

    // ---- pass 1 ----
    mfma_gemm<384, 256, true><<<dim3(2, rb, S_), 256, 0, stream>>>(
        feat1_bf, FIN, Wm1t, bm1, int1_bf, MO, cnt, perm);
    mfma_gemm32<256, true><<<dim3(1, rb32, S_), 256, 0, stream>>>(
        int1_bf, MO, Wn1t, bn1, neigh_bf, NO, cnt, perm);

    // ---- fused pass-1 gather + head, then charges ----
    gather_final<<<N / 4, 256, 0, stream>>>(
        neigh_bf, rowptr, ecol, ewgt, int1_bf, Wf, bf, species, out, N);
    charges_kernel<<<B, A, 0, stream>>>(out + 2 * (size_t)N, species, tc, out, N, A);
}

// Round 14
// 600.903 us; speedup vs baseline: 1.4374x; 1.0167x over previous
//
#include <hip/hip_runtime.h>
#include <hip/hip_bf16.h>
#include <math.h>

constexpr int S_  = 4;
constexpr int MO  = 256;
constexpr int NO  = 128;
constexpr int FIN = 384;
#define CUTOFF_F 5.2f

typedef short bf16x8 __attribute__((ext_vector_type(8)));
typedef float f32x16 __attribute__((ext_vector_type(16)));

__device__ __forceinline__ float gelu_tanh(float x) {
    float u = 0.7978845608028654f * (x + 0.044715f * x * x * x);
    return 0.5f * x * (1.0f + tanhf(u));
}
__device__ __forceinline__ unsigned short f2bf(float x) {   // RNE
    unsigned u = __float_as_uint(x);
    u = (u + 0x7fffu + ((u >> 16) & 1u)) >> 16;
    return (unsigned short)u;
}
__device__ __forceinline__ float bf2f(unsigned short h) {
    return __uint_as_float(((unsigned)h) << 16);
}
__device__ __forceinline__ float decay_of(float d, float fa, float pf) {
    float x = fminf(fmaxf(d / CUTOFF_F, 0.0f), 1.0f - 1e-6f);
    float f = expf(1.0f - 1.0f / (1.0f - x * x));
    float w = (d < CUTOFF_F) ? f : 0.0f;
    return pf * pf * expf(-(fa * fa) * d) * w;
}

// ---------------- species sort into PADDED sorted space ----------------
// cnt layout: [0..3]=counts, [4..7]=padded segment starts pofs[s], [8]=NP (padded total)
__global__ void species_hist(const int* __restrict__ sp, int* __restrict__ bhist, int N) {
    __shared__ int h[S_];
    int t = threadIdx.x, b = blockIdx.x;
    if (t < S_) h[t] = 0;
    __syncthreads();
    int i = b * 256 + t;
    if (i < N) {
        int s = sp[i];
        if (s >= 0 && s < S_) atomicAdd(&h[s], 1);
    }
    __syncthreads();
    if (t < S_) bhist[b * 4 + t] = h[t];
}
__global__ void species_scan(const int* __restrict__ bhist, int* __restrict__ cnt,
                             int* __restrict__ pbase, int nb) {
    if (threadIdx.x != 0) return;
    int tot[S_];
    for (int s = 0; s < S_; ++s) {
        int sum = 0;
        for (int b = 0; b < nb; ++b) sum += bhist[b * 4 + s];
        tot[s] = sum;
    }
    int off = 0;
    for (int s = 0; s < S_; ++s) {
        cnt[s] = tot[s];
        cnt[4 + s] = off;                       // padded start
        off += ((tot[s] + 63) / 64) * 64;       // pad segment to x64
    }
    cnt[8] = off;                               // NP
    for (int s = 0; s < S_; ++s) {
        int run = cnt[4 + s];
        for (int b = 0; b < nb; ++b) { pbase[b * 4 + s] = run; run += bhist[b * 4 + s]; }
    }
}
__global__ void species_fill(const int* __restrict__ sp, const int* __restrict__ pbase,
                             int* __restrict__ perm, int* __restrict__ inv_perm, int N) {
    __shared__ int cur[S_];
    int t = threadIdx.x, b = blockIdx.x;
    if (t < S_) cur[t] = pbase[b * 4 + t];
    __syncthreads();
    int i = b * 256 + t;
    if (i < N) {
        int s = sp[i];
        if (s >= 0 && s < S_) {
            int pos = atomicAdd(&cur[s], 1);
            perm[pos] = i;
            inv_perm[i] = pos;
        }
    }
}

// ---------------- gather-cast aev into sorted space (pad rows zeroed) ----------------
// one block per sorted row; 252 threads x ushort4 = 1008
__global__ void cast_gather(const float* __restrict__ aev, const int* __restrict__ perm,
                            unsigned short* __restrict__ outb, int AEV) {
    int row = blockIdx.x;
    int t = threadIdx.x;
    if (t * 4 >= AEV) return;
    int atom = perm[row];
    ushort4 o;
    if (atom >= 0) {
        float4 v = *(const float4*)(aev + (size_t)atom * AEV + t * 4);
        o.x = f2bf(v.x); o.y = f2bf(v.y); o.z = f2bf(v.z); o.w = f2bf(v.w);
    } else {
        o.x = o.y = o.z = o.w = 0;
    }
    *(ushort4*)(outb + (size_t)row * AEV + t * 4) = o;
}

// ---------------- edge CSR build in sorted space (decay fused) ----------------
__global__ void edge_count(const int* __restrict__ ai, const int* __restrict__ inv_perm,
                           int* __restrict__ degree, int P2) {
    int e = blockIdx.x * blockDim.x + threadIdx.x;
    if (e < P2) {
        int d = inv_perm[ai[e]];
        if (d >= 0) atomicAdd(&degree[d], 1);
    }
}
__global__ void scan_rowptr(const int* __restrict__ degree, int* __restrict__ rowptr,
                            int* __restrict__ cursor, int NSCAN) {
    __shared__ int lds[1024];
    int t = threadIdx.x;
    int per = NSCAN / 1024;
    int base = t * per;
    int sum = 0;
    for (int i = 0; i < per; ++i) sum += degree[base + i];
    lds[t] = sum;
    __syncthreads();
    int v = sum;
    for (int ofs = 1; ofs < 1024; ofs <<= 1) {
        int add = (t >= ofs) ? lds[t - ofs] : 0;
        __syncthreads();
        v += add;
        lds[t] = v;
        __syncthreads();
    }
    int run = v - sum;
    for (int i = 0; i < per; ++i) {
        int d = degree[base + i];
        rowptr[base + i] = run;
        cursor[base + i] = run;
        run += d;
    }
    if (t == 1023) rowptr[NSCAN] = run;
}
__global__ void edge_fill(const int* __restrict__ ai, const float* __restrict__ dist,
                          const float* __restrict__ fa_, const float* __restrict__ pf_,
                          const int* __restrict__ inv_perm,
                          int* __restrict__ cursor, int* __restrict__ col,
                          float* __restrict__ wgt, int P) {
    int e = blockIdx.x * blockDim.x + threadIdx.x;
    if (e >= 2 * P) return;
    int p = (e < P) ? e : e - P;
    int dst = inv_perm[ai[e]];
    if (dst < 0) return;
    int src = inv_perm[(e < P) ? ai[P + p] : ai[p]];
    int pos = atomicAdd(&cursor[dst], 1);
    col[pos] = (src >= 0) ? src : 0;
    wgt[pos] = (src >= 0) ? decay_of(dist[p], fa_[0], pf_[0]) : 0.0f;
}

// ---------------- weight transpose+cast:  W [S][K][NC] fp32 -> Wt [S][NC][K] bf16 ----------------
__global__ void transpose_cast(const float* __restrict__ W, unsigned short* __restrict__ Wt,
                               int K, int NC) {
    __shared__ float tile[32][33];
    int s = blockIdx.z;
    int nb = blockIdx.x * 32, kb = blockIdx.y * 32;
    int tx = threadIdx.x & 31, ty = threadIdx.x >> 5;
    const float* Wb = W + (size_t)s * K * NC;
    unsigned short* Wo = Wt + (size_t)s * NC * K;
#pragma unroll
    for (int i = 0; i < 4; ++i) {
        int k = kb + ty + i * 8;
        tile[ty + i * 8][tx] = (k < K) ? Wb[(size_t)k * NC + nb + tx] : 0.0f;
    }
    __syncthreads();
#pragma unroll
    for (int i = 0; i < 4; ++i) {
        int n = nb + ty + i * 8;
        int k = kb + tx;
        if (k < K) Wo[(size_t)n * K + k] = f2bf(tile[tx][ty + i * 8]);
    }
}

// ---------------- bf16 MFMA GEMM, 64x128 tile, sequential sorted rows ----------------
template<int K, int NC, bool ACT>
__launch_bounds__(256, 2)
__global__ void mfma_gemm(const unsigned short* __restrict__ A, int lda,
                          const unsigned short* __restrict__ Wt,
                          const float* __restrict__ bias,
                          unsigned short* __restrict__ C, int ldc,
                          const int* __restrict__ cnt) {
    const int row0 = blockIdx.y * 64;
    if (row0 >= cnt[8]) return;                   // beyond padded total
    const int s = (row0 >= cnt[5]) + (row0 >= cnt[6]) + (row0 >= cnt[7]);
    const int c0 = blockIdx.x * 128;

    __shared__ unsigned short As[64 * 40];
    __shared__ unsigned short Bs[128 * 40];

    const int t = threadIdx.x;
    const int lane = t & 63, wave = t >> 6;
    const int wm = wave >> 1, wn = wave & 1;
    const int l31 = lane & 31, lhi = lane >> 5;

    const int ra = t >> 2, qa = t & 3;
    const int rbr = t >> 1, hb = t & 1;
    const unsigned short* Arow = A + (size_t)(row0 + ra) * lda;
    const unsigned short* wrow = Wt + ((size_t)s * NC + c0 + rbr) * K;

    f32x16 acc0 = {}, acc1 = {};
    const uint4 z4 = {0, 0, 0, 0};

    for (int k0 = 0; k0 < K; k0 += 32) {
        const int ka = k0 + qa * 8;
        uint4 av = z4;
        if (ka < K) av = *(const uint4*)(Arow + ka);
        const int kb = k0 + hb * 16;
        uint4 b0 = z4, b1 = z4;
        if (kb < K) {
            const uint4* q = (const uint4*)(wrow + kb);
            b0 = q[0]; b1 = q[1];
        }
        __syncthreads();
        *(uint4*)(&As[ra * 40 + qa * 8]) = av;
        *(uint4*)(&Bs[rbr * 40 + hb * 16])     = b0;
        *(uint4*)(&Bs[rbr * 40 + hb * 16 + 8]) = b1;
        __syncthreads();
#pragma unroll
        for (int ks = 0; ks < 2; ++ks) {
            const int ch = (ks * 2 + lhi) * 8;
            bf16x8 fa  = *(const bf16x8*)(&As[(wm * 32 + l31) * 40 + ch]);
            bf16x8 fb0 = *(const bf16x8*)(&Bs[(wn * 64 +  0 + l31) * 40 + ch]);
            bf16x8 fb1 = *(const bf16x8*)(&Bs[(wn * 64 + 32 + l31) * 40 + ch]);
            acc0 = __builtin_amdgcn_mfma_f32_32x32x16_bf16(fa, fb0, acc0, 0, 0, 0);
            acc1 = __builtin_amdgcn_mfma_f32_32x32x16_bf16(fa, fb1, acc1, 0, 0, 0);
        }
    }

    const float* bp = bias + s * NC;
    auto store = [&](const f32x16& vv, int fn) {
        int col = c0 + wn * 64 + fn * 32 + l31;
        float bia = bp[col];
#pragma unroll
        for (int reg = 0; reg < 16; ++reg) {
            int frow = (reg & 3) + 8 * (reg >> 2) + 4 * lhi;   // verified C/D layout
            int r = row0 + wm * 32 + frow;
            float x = vv[reg] + bia;
            if (ACT) x = gelu_tanh(x);
            C[(size_t)r * ldc + col] = f2bf(x);
        }
    };
    store(acc0, 0); store(acc1, 1);
}

// ---------------- bf16 MFMA GEMM, 32x128 tile (NC=128), sequential sorted rows ----------------
template<int K, bool ACT>
__launch_bounds__(256, 2)
__global__ void mfma_gemm32(const unsigned short* __restrict__ A, int lda,
                            const unsigned short* __restrict__ Wt,
                            const float* __restrict__ bias,
                            unsigned short* __restrict__ C, int ldc,
                            const int* __restrict__ cnt) {
    const int row0 = blockIdx.y * 32;
    if (row0 >= cnt[8]) return;
    const int s = (row0 >= cnt[5]) + (row0 >= cnt[6]) + (row0 >= cnt[7]);
    constexpr int NC = 128;

    __shared__ unsigned short As[32 * 40];
    __shared__ unsigned short Bs[128 * 40];

    const int t = threadIdx.x;
    const int lane = t & 63, wave = t >> 6;
    const int l31 = lane & 31, lhi = lane >> 5;

    const int ra = t >> 3, qa = t & 7;
    const int rbr = t >> 1, hb = t & 1;
    const unsigned short* Arow = A + (size_t)(row0 + ra) * lda;
    const unsigned short* wrow = Wt + ((size_t)s * NC + rbr) * K;

    f32x16 acc = {};
    const uint4 z4 = {0, 0, 0, 0};
    const uint2 z2 = {0, 0};

    for (int k0 = 0; k0 < K; k0 += 32) {
        const int ka = k0 + qa * 4;
        uint2 av = z2;
        if (ka < K) av = *(const uint2*)(Arow + ka);
        const int kb = k0 + hb * 16;
        uint4 b0 = z4, b1 = z4;
        if (kb < K) {
            const uint4* q = (const uint4*)(wrow + kb);
            b0 = q[0]; b1 = q[1];
        }
        __syncthreads();
        *(uint2*)(&As[ra * 40 + qa * 4]) = av;
        *(uint4*)(&Bs[rbr * 40 + hb * 16])     = b0;
        *(uint4*)(&Bs[rbr * 40 + hb * 16 + 8]) = b1;
        __syncthreads();
#pragma unroll
        for (int ks = 0; ks < 2; ++ks) {
            const int ch = (ks * 2 + lhi) * 8;
            bf16x8 fa = *(const bf16x8*)(&As[l31 * 40 + ch]);
            bf16x8 fb = *(const bf16x8*)(&Bs[(wave * 32 + l31) * 40 + ch]);
            acc = __builtin_amdgcn_mfma_f32_32x32x16_bf16(fa, fb, acc, 0, 0, 0);
        }
    }

    const float* bp = bias + s * NC;
    int col = wave * 32 + l31;
    float bia = bp[col];
#pragma unroll
    for (int reg = 0; reg < 16; ++reg) {
        int frow = (reg & 3) + 8 * (reg >> 2) + 4 * lhi;
        int r = row0 + frow;
        float x = acc[reg] + bia;
        if (ACT) x = gelu_tanh(x);
        C[(size_t)r * ldc + col] = f2bf(x);
    }
}

// ---------------- CSR gather-reduce (sorted space), unroll x4, pass 0 ----------------
__global__ void gather_rows0(const unsigned short* __restrict__ neigh,
                             const int* __restrict__ rowptr, const int* __restrict__ col,
                             const float* __restrict__ wgt,
                             unsigned short* __restrict__ featout) {
    int row = blockIdx.x * 4 + (threadIdx.x >> 6);
    int lane = threadIdx.x & 63;
    int b = rowptr[row], e = rowptr[row + 1];
    int j = lane * 2;
    float a0 = 0.f, a1 = 0.f, c0 = 0.f, c1 = 0.f;
    int i = b;
    for (; i + 3 < e; i += 4) {
        int s0 = col[i], s1 = col[i + 1], s2 = col[i + 2], s3 = col[i + 3];
        float w0 = wgt[i], w1 = wgt[i + 1], w2 = wgt[i + 2], w3 = wgt[i + 3];
        unsigned p0 = *(const unsigned*)(neigh + (size_t)s0 * NO + j);
        unsigned p1 = *(const unsigned*)(neigh + (size_t)s1 * NO + j);
        unsigned p2 = *(const unsigned*)(neigh + (size_t)s2 * NO + j);
        unsigned p3 = *(const unsigned*)(neigh + (size_t)s3 * NO + j);
        a0 += bf2f((unsigned short)(p0 & 0xffffu)) * w0 + bf2f((unsigned short)(p2 & 0xffffu)) * w2;
        a1 += bf2f((unsigned short)(p0 >> 16)) * w0 + bf2f((unsigned short)(p2 >> 16)) * w2;
        c0 += bf2f((unsigned short)(p1 & 0xffffu)) * w1 + bf2f((unsigned short)(p3 & 0xffffu)) * w3;
        c1 += bf2f((unsigned short)(p1 >> 16)) * w1 + bf2f((unsigned short)(p3 >> 16)) * w3;
    }
    for (; i < e; ++i) {
        int s0 = col[i];
        float w0 = wgt[i];
        unsigned p0 = *(const unsigned*)(neigh + (size_t)s0 * NO + j);
        a0 += bf2f((unsigned short)(p0 & 0xffffu)) * w0;
        a1 += bf2f((unsigned short)(p0 >> 16)) * w0;
    }
    a0 += c0; a1 += c1;
    unsigned short o0 = f2bf(a0), o1 = f2bf(a1);
    *(unsigned*)(featout + (size_t)row * FIN + MO + j) = ((unsigned)o1 << 16) | (unsigned)o0;
}

// ---------------- fused pass-1 gather + final head (sorted space -> atom output) ----------------
__global__ void gather_final(const unsigned short* __restrict__ neigh,
                             const int* __restrict__ rowptr, const int* __restrict__ col,
                             const float* __restrict__ wgt,
                             const unsigned short* __restrict__ int1,
                             const int* __restrict__ perm,
                             const int* __restrict__ species,
                             const float* __restrict__ Wf, const float* __restrict__ bfb,
                             float* __restrict__ out, int N) {
    int w = blockIdx.x * 4 + (threadIdx.x >> 6);
    int lane = threadIdx.x & 63;
    int atom = perm[w];
    if (atom < 0) return;
    int s = species[atom];
    float acc = 0.0f;
    if (s >= 0) {
        const float* wp = Wf + (size_t)s * FIN;
        int b = rowptr[w], e = rowptr[w + 1];
        int j = lane * 2;
        float a0 = 0.f, a1 = 0.f, c0 = 0.f, c1 = 0.f;
        int i = b;
        for (; i + 3 < e; i += 4) {
            int s0 = col[i], s1 = col[i + 1], s2 = col[i + 2], s3 = col[i + 3];
            float w0 = wgt[i], w1 = wgt[i + 1], w2 = wgt[i + 2], w3 = wgt[i + 3];
            unsigned p0 = *(const unsigned*)(neigh + (size_t)s0 * NO + j);
            unsigned p1 = *(const unsigned*)(neigh + (size_t)s1 * NO + j);
            unsigned p2 = *(const unsigned*)(neigh + (size_t)s2 * NO + j);
            unsigned p3 = *(const unsigned*)(neigh + (size_t)s3 * NO + j);
            a0 += bf2f((unsigned short)(p0 & 0xffffu)) * w0 + bf2f((unsigned short)(p2 & 0xffffu)) * w2;
            a1 += bf2f((unsigned short)(p0 >> 16)) * w0 + bf2f((unsigned short)(p2 >> 16)) * w2;
            c0 += bf2f((unsigned short)(p1 & 0xffffu)) * w1 + bf2f((unsigned short)(p3 & 0xffffu)) * w3;
            c1 += bf2f((unsigned short)(p1 >> 16)) * w1 + bf2f((unsigned short)(p3 >> 16)) * w3;
        }
        for (; i < e; ++i) {
            int s0 = col[i];
            float w0 = wgt[i];
            unsigned p0 = *(const unsigned*)(neigh + (size_t)s0 * NO + j);
            a0 += bf2f((unsigned short)(p0 & 0xffffu)) * w0;
            a1 += bf2f((unsigned short)(p0 >> 16)) * w0;
        }
        a0 += c0; a1 += c1;
        acc = a0 * wp[MO + j] + a1 * wp[MO + j + 1];
        const unsigned short* ip = int1 + (size_t)w * MO + lane * 4;
        ushort4 iv = *(const ushort4*)ip;
        const float* wq = wp + lane * 4;
        acc += bf2f(iv.x) * wq[0] + bf2f(iv.y) * wq[1] + bf2f(iv.z) * wq[2] + bf2f(iv.w) * wq[3];
    }
    for (int o = 32; o > 0; o >>= 1) acc += __shfl_down(acc, o, 64);
    if (lane == 0) {
        float pre = (s >= 0) ? (acc + bfb[s]) : 0.0f;
        out[2 * (size_t)N + atom] = pre;
        out[atom] = (float)s;
    }
}

// ---------------- per-batch charge correction ----------------
__global__ void charges_kernel(const float* __restrict__ pre_buf, const int* __restrict__ species,
                               const float* __restrict__ tc, float* __restrict__ out, int N, int A) {
    int b = blockIdx.x;
    int a = threadIdx.x;
    int idx = b * A + a;
    float pre = pre_buf[idx];
    int sp = species[idx];
    bool mask = (sp != -1);
    float v = pre;
    int c = mask ? 1 : 0;
    for (int o = 32; o > 0; o >>= 1) {
        v += __shfl_down(v, o, 64);
        c += __shfl_down(c, o, 64);
    }
    __shared__ float ssum[2];
    __shared__ int scnt[2];
    int wid = threadIdx.x >> 6;
    if ((threadIdx.x & 63) == 0) { ssum[wid] = v; scnt[wid] = c; }
    __syncthreads();
    float total = ssum[0] + ssum[1];
    int nreal = scnt[0] + scnt[1];
    float ch = pre + (tc[b] - total) / (float)max(nreal, 1);
    out[(size_t)N + idx] = mask ? ch : 0.0f;
}

extern "C" void kernel_launch(void* const* d_in, const int* in_sizes, int n_in,
                              void* d_out, int out_size, void* d_ws, size_t ws_size,
                              hipStream_t stream) {
    const int*   species = (const int*)d_in[0];
    const float* aev     = (const float*)d_in[1];
    const int*   ai      = (const int*)d_in[2];
    const float* dist    = (const float*)d_in[3];
    const float* tc      = (const float*)d_in[4];
    const float* Wm0 = (const float*)d_in[5];  const float* bm0 = (const float*)d_in[6];
    const float* Wn0 = (const float*)d_in[7];  const float* bn0 = (const float*)d_in[8];
    const float* Wm1 = (const float*)d_in[9];  const float* bm1 = (const float*)d_in[10];
    const float* Wn1 = (const float*)d_in[11]; const float* bn1 = (const float*)d_in[12];
    const float* Wf  = (const float*)d_in[13]; const float* bf  = (const float*)d_in[14];
    const float* factor    = (const float*)d_in[15];
    const float* prefactor = (const float*)d_in[16];

    const int N   = in_sizes[0];
    const int AEV = in_sizes[1] / N;       // 1008
    const int P   = in_sizes[3];
    const int B   = in_sizes[4];
    const int A   = N / B;

    const int NPAD  = N + 256;                          // max padded sorted rows
    const int NSCAN = ((NPAD + 1023) / 1024) * 1024;    // scan granularity

    float* out = (float*)d_out;

    // ---- workspace layout ----
    char* base = (char*)d_ws;
    size_t o = 0;
    auto take = [&](size_t bytes) -> char* {
        o = (o + 255) & ~(size_t)255;
        char* p = base + o; o += bytes; return p;
    };
    unsigned short* feat1_bf = (unsigned short*)take((size_t)NPAD * FIN * 2);
    unsigned short* int1_bf  = (unsigned short*)take((size_t)NPAD * MO * 2);
    char* region             = take((size_t)NPAD * AEV * 2);
    // region overlay: aev_bf (dead after GEMM1) | neigh_bf | CSR arrays
    unsigned short* aev_bf   = (unsigned short*)region;
    unsigned short* neigh_bf = (unsigned short*)region;
    size_t roff = ((size_t)NPAD * NO * 2 + 255) & ~(size_t)255;
    int* rowptr = (int*)(region + roff);  roff += (size_t)(NSCAN + 1) * 4; roff = (roff + 255) & ~(size_t)255;
    int* cursor = (int*)(region + roff);  roff += (size_t)NSCAN * 4;       roff = (roff + 255) & ~(size_t)255;
    int* degree = (int*)(region + roff);  roff += (size_t)NSCAN * 4;       roff = (roff + 255) & ~(size_t)255;
    int* ecol   = (int*)(region + roff);  roff += (size_t)2 * P * 4;       roff = (roff + 255) & ~(size_t)255;
    float* ewgt = (float*)(region + roff);
    unsigned short* Wm0t = (unsigned short*)take((size_t)S_ * MO * AEV * 2);
    unsigned short* Wn0t = (unsigned short*)take((size_t)S_ * NO * MO * 2);
    unsigned short* Wm1t = (unsigned short*)take((size_t)S_ * MO * FIN * 2);
    unsigned short* Wn1t = (unsigned short*)take((size_t)S_ * NO * MO * 2);
    int* perm     = (int*)take((size_t)NPAD * 4);
    int* inv_perm = (int*)take((size_t)N * 4);
    int* cnt      = (int*)take(64);
    const int nb = (N + 255) / 256;
    int* bhist = (int*)take((size_t)nb * 4 * 4);
    int* pbase = (int*)take((size_t)nb * 4 * 4);

    // ---- species sort into padded sorted space ----
    hipMemsetAsync(perm, 0xFF, (size_t)NPAD * 4, stream);       // -1
    hipMemsetAsync(inv_perm, 0xFF, (size_t)N * 4, stream);      // -1
    species_hist<<<nb, 256, 0, stream>>>(species, bhist, N);
    species_scan<<<1, 64, 0, stream>>>(bhist, cnt, pbase, nb);
    species_fill<<<nb, 256, 0, stream>>>(species, pbase, perm, inv_perm, N);

    // ---- gather-cast aev into sorted space; weight transposes ----
    cast_gather<<<NPAD, 256, 0, stream>>>(aev, perm, aev_bf, AEV);
    transpose_cast<<<dim3(MO / 32, (AEV + 31) / 32, S_), 256, 0, stream>>>(Wm0, Wm0t, AEV, MO);
    transpose_cast<<<dim3(NO / 32, MO / 32, S_), 256, 0, stream>>>(Wn0, Wn0t, MO, NO);
    transpose_cast<<<dim3(MO / 32, FIN / 32, S_), 256, 0, stream>>>(Wm1, Wm1t, FIN, MO);
    transpose_cast<<<dim3(NO / 32, MO / 32, S_), 256, 0, stream>>>(Wn1, Wn1t, MO, NO);

    const int T64 = NPAD / 64;
    const int T32 = NPAD / 32;

    // ---- pass 0: GEMM1 (sequential rows), then CSR build in aev_bf's memory ----
    mfma_gemm<1008, 256, true><<<dim3(2, T64), 256, 0, stream>>>(
        aev_bf, AEV, Wm0t, bm0, feat1_bf, FIN, cnt);

    hipMemsetAsync(degree, 0, (size_t)NSCAN * 4, stream);
    edge_count<<<(2 * P + 255) / 256, 256, 0, stream>>>(ai, inv_perm, degree, 2 * P);
    scan_rowptr<<<1, 1024, 0, stream>>>(degree, rowptr, cursor, NSCAN);
    edge_fill<<<(2 * P + 255) / 256, 256, 0, stream>>>(ai, dist, factor, prefactor,
                                                       inv_perm, cursor, ecol, ewgt, P);

    mfma_gemm32<256, true><<<dim3(1, T32), 256, 0, stream>>>(
        feat1_bf, FIN, Wn0t, bn0, neigh_bf, NO, cnt);
    gather_rows0<<<NPAD / 4, 256, 0, stream>>>(neigh_bf, rowptr, ecol, ewgt, feat1_bf);

    // ---- pass 1 ----
    mfma_gemm<384, 256, true><<<dim3(2, T64), 256, 0, stream>>>(
        feat1_bf, FIN, Wm1t, bm1, int1_bf, MO, cnt);
    mfma_gemm32<256, true><<<dim3(1, T32), 256, 0, stream>>>(
        int1_bf, MO, Wn1t, bn1, neigh_bf, NO, cnt);

    // ---- fused pass-1 gather + head, then charges ----
    gather_final<<<NPAD / 4, 256, 0, stream>>>(
        neigh_bf, rowptr, ecol, ewgt, int1_bf, perm, species, Wf, bf, out, N);
    charges_kernel<<<B, A, 0, stream>>>(out + 2 * (size_t)N, species, tc, out, N, A);
}

// Round 15
// 595.540 us; speedup vs baseline: 1.4503x; 1.0090x over previous
//
#include <hip/hip_runtime.h>
#include <hip/hip_bf16.h>
#include <math.h>

constexpr int S_  = 4;
constexpr int MO  = 256;
constexpr int NO  = 128;
constexpr int FIN = 384;
#define CUTOFF_F 5.2f

typedef short bf16x8 __attribute__((ext_vector_type(8)));
typedef float f32x16 __attribute__((ext_vector_type(16)));

__device__ __forceinline__ float gelu_tanh(float x) {
    float u = 0.7978845608028654f * (x + 0.044715f * x * x * x);
    return 0.5f * x * (1.0f + tanhf(u));
}
__device__ __forceinline__ unsigned short f2bf(float x) {   // RNE
    unsigned u = __float_as_uint(x);
    u = (u + 0x7fffu + ((u >> 16) & 1u)) >> 16;
    return (unsigned short)u;
}
__device__ __forceinline__ float bf2f(unsigned short h) {
    return __uint_as_float(((unsigned)h) << 16);
}
__device__ __forceinline__ float decay_of(float d, float fa, float pf) {
    float x = fminf(fmaxf(d / CUTOFF_F, 0.0f), 1.0f - 1e-6f);
    float f = expf(1.0f - 1.0f / (1.0f - x * x));
    float w = (d < CUTOFF_F) ? f : 0.0f;
    return pf * pf * expf(-(fa * fa) * d) * w;
}

// ---------------- species sort into PADDED sorted space ----------------
// cnt layout: [0..3]=counts, [4..7]=padded segment starts, [8]=NP (padded total)
__global__ void species_hist(const int* __restrict__ sp, int* __restrict__ bhist, int N) {
    __shared__ int h[S_];
    int t = threadIdx.x, b = blockIdx.x;
    if (t < S_) h[t] = 0;
    __syncthreads();
    int i = b * 256 + t;
    if (i < N) {
        int s = sp[i];
        if (s >= 0 && s < S_) atomicAdd(&h[s], 1);
    }
    __syncthreads();
    if (t < S_) bhist[b * 4 + t] = h[t];
}
__global__ void species_scan(const int* __restrict__ bhist, int* __restrict__ cnt,
                             int* __restrict__ pbase, int nb) {
    if (threadIdx.x != 0) return;
    int tot[S_];
    for (int s = 0; s < S_; ++s) {
        int sum = 0;
        for (int b = 0; b < nb; ++b) sum += bhist[b * 4 + s];
        tot[s] = sum;
    }
    int off = 0;
    for (int s = 0; s < S_; ++s) {
        cnt[s] = tot[s];
        cnt[4 + s] = off;
        off += ((tot[s] + 63) / 64) * 64;
    }
    cnt[8] = off;
    for (int s = 0; s < S_; ++s) {
        int run = cnt[4 + s];
        for (int b = 0; b < nb; ++b) { pbase[b * 4 + s] = run; run += bhist[b * 4 + s]; }
    }
}
__global__ void species_fill(const int* __restrict__ sp, const int* __restrict__ pbase,
                             int* __restrict__ perm, int* __restrict__ inv_perm, int N) {
    __shared__ int cur[S_];
    int t = threadIdx.x, b = blockIdx.x;
    if (t < S_) cur[t] = pbase[b * 4 + t];
    __syncthreads();
    int i = b * 256 + t;
    if (i < N) {
        int s = sp[i];
        if (s >= 0 && s < S_) {
            int pos = atomicAdd(&cur[s], 1);
            perm[pos] = i;
            inv_perm[i] = pos;
        }
    }
}

// ---------------- gather-cast aev into sorted space (pad rows zeroed) ----------------
__global__ void cast_gather(const float* __restrict__ aev, const int* __restrict__ perm,
                            unsigned short* __restrict__ outb, int AEV) {
    int row = blockIdx.x;
    int t = threadIdx.x;
    if (t * 4 >= AEV) return;
    int atom = perm[row];
    ushort4 o;
    if (atom >= 0) {
        float4 v = *(const float4*)(aev + (size_t)atom * AEV + t * 4);
        o.x = f2bf(v.x); o.y = f2bf(v.y); o.z = f2bf(v.z); o.w = f2bf(v.w);
    } else {
        o.x = o.y = o.z = o.w = 0;
    }
    *(ushort4*)(outb + (size_t)row * AEV + t * 4) = o;
}

// ---------------- edge CSR build in sorted space (decay fused) ----------------
__global__ void edge_count(const int* __restrict__ ai, const int* __restrict__ inv_perm,
                           int* __restrict__ degree, int P2) {
    int e = blockIdx.x * blockDim.x + threadIdx.x;
    if (e < P2) {
        int d = inv_perm[ai[e]];
        if (d >= 0) atomicAdd(&degree[d], 1);
    }
}
__global__ void scan_rowptr(const int* __restrict__ degree, int* __restrict__ rowptr,
                            int* __restrict__ cursor, int NSCAN) {
    __shared__ int lds[1024];
    int t = threadIdx.x;
    int per = NSCAN / 1024;
    int base = t * per;
    int sum = 0;
    for (int i = 0; i < per; ++i) sum += degree[base + i];
    lds[t] = sum;
    __syncthreads();
    int v = sum;
    for (int ofs = 1; ofs < 1024; ofs <<= 1) {
        int add = (t >= ofs) ? lds[t - ofs] : 0;
        __syncthreads();
        v += add;
        lds[t] = v;
        __syncthreads();
    }
    int run = v - sum;
    for (int i = 0; i < per; ++i) {
        int d = degree[base + i];
        rowptr[base + i] = run;
        cursor[base + i] = run;
        run += d;
    }
    if (t == 1023) rowptr[NSCAN] = run;
}
__global__ void edge_fill(const int* __restrict__ ai, const float* __restrict__ dist,
                          const float* __restrict__ fa_, const float* __restrict__ pf_,
                          const int* __restrict__ inv_perm,
                          int* __restrict__ cursor, int* __restrict__ col,
                          float* __restrict__ wgt, int P) {
    int e = blockIdx.x * blockDim.x + threadIdx.x;
    if (e >= 2 * P) return;
    int p = (e < P) ? e : e - P;
    int dst = inv_perm[ai[e]];
    if (dst < 0) return;
    int src = inv_perm[(e < P) ? ai[P + p] : ai[p]];
    int pos = atomicAdd(&cursor[dst], 1);
    col[pos] = (src >= 0) ? src : 0;
    wgt[pos] = (src >= 0) ? decay_of(dist[p], fa_[0], pf_[0]) : 0.0f;
}

// ---------------- weight transpose+cast:  W [S][K][NC] fp32 -> Wt [S][NC][K] bf16 ----------------
__global__ void transpose_cast(const float* __restrict__ W, unsigned short* __restrict__ Wt,
                               int K, int NC) {
    __shared__ float tile[32][33];
    int s = blockIdx.z;
    int nb = blockIdx.x * 32, kb = blockIdx.y * 32;
    int tx = threadIdx.x & 31, ty = threadIdx.x >> 5;
    const float* Wb = W + (size_t)s * K * NC;
    unsigned short* Wo = Wt + (size_t)s * NC * K;
#pragma unroll
    for (int i = 0; i < 4; ++i) {
        int k = kb + ty + i * 8;
        tile[ty + i * 8][tx] = (k < K) ? Wb[(size_t)k * NC + nb + tx] : 0.0f;
    }
    __syncthreads();
#pragma unroll
    for (int i = 0; i < 4; ++i) {
        int n = nb + ty + i * 8;
        int k = kb + tx;
        if (k < K) Wo[(size_t)n * K + k] = f2bf(tile[tx][ty + i * 8]);
    }
}

// ---------------- bf16 MFMA GEMM, 64x128, sequential rows, issue-early pipeline ----------------
// Per iter: stage(regs->LDS) | barrier | prefetch(it+1) issue | MFMA | barrier.
// Loads stay in flight across MFMA+barrier instead of draining cold each iteration.
template<int K, int NC, bool ACT>
__launch_bounds__(256, 2)
__global__ void mfma_gemm(const unsigned short* __restrict__ A, int lda,
                          const unsigned short* __restrict__ Wt,
                          const float* __restrict__ bias,
                          unsigned short* __restrict__ C, int ldc,
                          const int* __restrict__ cnt) {
    const int row0 = blockIdx.y * 64;
    if (row0 >= cnt[8]) return;
    const int s = (row0 >= cnt[5]) + (row0 >= cnt[6]) + (row0 >= cnt[7]);
    const int c0 = blockIdx.x * 128;

    __shared__ unsigned short As[64 * 40];
    __shared__ unsigned short Bs[128 * 40];

    const int t = threadIdx.x;
    const int lane = t & 63, wave = t >> 6;
    const int wm = wave >> 1, wn = wave & 1;
    const int l31 = lane & 31, lhi = lane >> 5;

    const int ra = t >> 2, qa = t & 3;
    const int rbr = t >> 1, hb = t & 1;
    const unsigned short* Arow = A + (size_t)(row0 + ra) * lda;
    const unsigned short* wrow = Wt + ((size_t)s * NC + c0 + rbr) * K;

    f32x16 acc0 = {}, acc1 = {};
    const uint4 z4 = {0, 0, 0, 0};
    uint4 pav, pb0, pb1;

    auto prefetch = [&](int it) {
        const int ka = it * 32 + qa * 8;
        pav = z4;
        if (ka < K) pav = *(const uint4*)(Arow + ka);
        const int kb = it * 32 + hb * 16;
        pb0 = z4; pb1 = z4;
        if (kb < K) {
            const uint4* q = (const uint4*)(wrow + kb);
            pb0 = q[0]; pb1 = q[1];
        }
    };

    const int NIT = (K + 31) / 32;
    prefetch(0);

    for (int it = 0; it < NIT; ++it) {
        *(uint4*)(&As[ra * 40 + qa * 8]) = pav;           // waits on in-flight loads here
        *(uint4*)(&Bs[rbr * 40 + hb * 16])     = pb0;
        *(uint4*)(&Bs[rbr * 40 + hb * 16 + 8]) = pb1;
        __syncthreads();                                   // LDS visible
        if (it + 1 < NIT) prefetch(it + 1);                // issue next loads now
#pragma unroll
        for (int ks = 0; ks < 2; ++ks) {
            const int ch = (ks * 2 + lhi) * 8;
            bf16x8 fa  = *(const bf16x8*)(&As[(wm * 32 + l31) * 40 + ch]);
            bf16x8 fb0 = *(const bf16x8*)(&Bs[(wn * 64 +  0 + l31) * 40 + ch]);
            bf16x8 fb1 = *(const bf16x8*)(&Bs[(wn * 64 + 32 + l31) * 40 + ch]);
            acc0 = __builtin_amdgcn_mfma_f32_32x32x16_bf16(fa, fb0, acc0, 0, 0, 0);
            acc1 = __builtin_amdgcn_mfma_f32_32x32x16_bf16(fa, fb1, acc1, 0, 0, 0);
        }
        __syncthreads();                                   // MFMA reads done before overwrite
    }

    const float* bp = bias + s * NC;
    auto store = [&](const f32x16& vv, int fn) {
        int col = c0 + wn * 64 + fn * 32 + l31;
        float bia = bp[col];
#pragma unroll
        for (int reg = 0; reg < 16; ++reg) {
            int frow = (reg & 3) + 8 * (reg >> 2) + 4 * lhi;   // verified C/D layout
            int r = row0 + wm * 32 + frow;
            float x = vv[reg] + bia;
            if (ACT) x = gelu_tanh(x);
            C[(size_t)r * ldc + col] = f2bf(x);
        }
    };
    store(acc0, 0); store(acc1, 1);
}

// ---------------- bf16 MFMA GEMM, 32x128 (NC=128), issue-early pipeline ----------------
template<int K, bool ACT>
__launch_bounds__(256, 2)
__global__ void mfma_gemm32(const unsigned short* __restrict__ A, int lda,
                            const unsigned short* __restrict__ Wt,
                            const float* __restrict__ bias,
                            unsigned short* __restrict__ C, int ldc,
                            const int* __restrict__ cnt) {
    const int row0 = blockIdx.y * 32;
    if (row0 >= cnt[8]) return;
    const int s = (row0 >= cnt[5]) + (row0 >= cnt[6]) + (row0 >= cnt[7]);
    constexpr int NC = 128;

    __shared__ unsigned short As[32 * 40];
    __shared__ unsigned short Bs[128 * 40];

    const int t = threadIdx.x;
    const int lane = t & 63, wave = t >> 6;
    const int l31 = lane & 31, lhi = lane >> 5;

    const int ra = t >> 3, qa = t & 7;
    const int rbr = t >> 1, hb = t & 1;
    const unsigned short* Arow = A + (size_t)(row0 + ra) * lda;
    const unsigned short* wrow = Wt + ((size_t)s * NC + rbr) * K;

    f32x16 acc = {};
    const uint4 z4 = {0, 0, 0, 0};
    const uint2 z2 = {0, 0};
    uint2 pav;
    uint4 pb0, pb1;

    auto prefetch = [&](int it) {
        const int ka = it * 32 + qa * 4;
        pav = z2;
        if (ka < K) pav = *(const uint2*)(Arow + ka);
        const int kb = it * 32 + hb * 16;
        pb0 = z4; pb1 = z4;
        if (kb < K) {
            const uint4* q = (const uint4*)(wrow + kb);
            pb0 = q[0]; pb1 = q[1];
        }
    };

    const int NIT = (K + 31) / 32;
    prefetch(0);

    for (int it = 0; it < NIT; ++it) {
        *(uint2*)(&As[ra * 40 + qa * 4]) = pav;
        *(uint4*)(&Bs[rbr * 40 + hb * 16])     = pb0;
        *(uint4*)(&Bs[rbr * 40 + hb * 16 + 8]) = pb1;
        __syncthreads();
        if (it + 1 < NIT) prefetch(it + 1);
#pragma unroll
        for (int ks = 0; ks < 2; ++ks) {
            const int ch = (ks * 2 + lhi) * 8;
            bf16x8 fa = *(const bf16x8*)(&As[l31 * 40 + ch]);
            bf16x8 fb = *(const bf16x8*)(&Bs[(wave * 32 + l31) * 40 + ch]);
            acc = __builtin_amdgcn_mfma_f32_32x32x16_bf16(fa, fb, acc, 0, 0, 0);
        }
        __syncthreads();
    }

    const float* bp = bias + s * NC;
    int col = wave * 32 + l31;
    float bia = bp[col];
#pragma unroll
    for (int reg = 0; reg < 16; ++reg) {
        int frow = (reg & 3) + 8 * (reg >> 2) + 4 * lhi;
        int r = row0 + frow;
        float x = acc[reg] + bia;
        if (ACT) x = gelu_tanh(x);
        C[(size_t)r * ldc + col] = f2bf(x);
    }
}

// ---------------- CSR gather-reduce (sorted space), unroll x4, pass 0 ----------------
__global__ void gather_rows0(const unsigned short* __restrict__ neigh,
                             const int* __restrict__ rowptr, const int* __restrict__ col,
                             const float* __restrict__ wgt,
                             unsigned short* __restrict__ featout) {
    int row = blockIdx.x * 4 + (threadIdx.x >> 6);
    int lane = threadIdx.x & 63;
    int b = rowptr[row], e = rowptr[row + 1];
    int j = lane * 2;
    float a0 = 0.f, a1 = 0.f, c0 = 0.f, c1 = 0.f;
    int i = b;
    for (; i + 3 < e; i += 4) {
        int s0 = col[i], s1 = col[i + 1], s2 = col[i + 2], s3 = col[i + 3];
        float w0 = wgt[i], w1 = wgt[i + 1], w2 = wgt[i + 2], w3 = wgt[i + 3];
        unsigned p0 = *(const unsigned*)(neigh + (size_t)s0 * NO + j);
        unsigned p1 = *(const unsigned*)(neigh + (size_t)s1 * NO + j);
        unsigned p2 = *(const unsigned*)(neigh + (size_t)s2 * NO + j);
        unsigned p3 = *(const unsigned*)(neigh + (size_t)s3 * NO + j);
        a0 += bf2f((unsigned short)(p0 & 0xffffu)) * w0 + bf2f((unsigned short)(p2 & 0xffffu)) * w2;
        a1 += bf2f((unsigned short)(p0 >> 16)) * w0 + bf2f((unsigned short)(p2 >> 16)) * w2;
        c0 += bf2f((unsigned short)(p1 & 0xffffu)) * w1 + bf2f((unsigned short)(p3 & 0xffffu)) * w3;
        c1 += bf2f((unsigned short)(p1 >> 16)) * w1 + bf2f((unsigned short)(p3 >> 16)) * w3;
    }
    for (; i < e; ++i) {
        int s0 = col[i];
        float w0 = wgt[i];
        unsigned p0 = *(const unsigned*)(neigh + (size_t)s0 * NO + j);
        a0 += bf2f((unsigned short)(p0 & 0xffffu)) * w0;
        a1 += bf2f((unsigned short)(p0 >> 16)) * w0;
    }
    a0 += c0; a1 += c1;
    unsigned short o0 = f2bf(a0), o1 = f2bf(a1);
    *(unsigned*)(featout + (size_t)row * FIN + MO + j) = ((unsigned)o1 << 16) | (unsigned)o0;
}

// ---------------- fused pass-1 gather + final head (sorted space -> atom output) ----------------
__global__ void gather_final(const unsigned short* __restrict__ neigh,
                             const int* __restrict__ rowptr, const int* __restrict__ col,
                             const float* __restrict__ wgt,
                             const unsigned short* __restrict__ int1,
                             const int* __restrict__ perm,
                             const int* __restrict__ species,
                             const float* __restrict__ Wf, const float* __restrict__ bfb,
                             float* __restrict__ out, int N) {
    int w = blockIdx.x * 4 + (threadIdx.x >> 6);
    int lane = threadIdx.x & 63;
    int atom = perm[w];
    if (atom < 0) return;
    int s = species[atom];
    float acc = 0.0f;
    if (s >= 0) {
        const float* wp = Wf + (size_t)s * FIN;
        int b = rowptr[w], e = rowptr[w + 1];
        int j = lane * 2;
        float a0 = 0.f, a1 = 0.f, c0 = 0.f, c1 = 0.f;
        int i = b;
        for (; i + 3 < e; i += 4) {
            int s0 = col[i], s1 = col[i + 1], s2 = col[i + 2], s3 = col[i + 3];
            float w0 = wgt[i], w1 = wgt[i + 1], w2 = wgt[i + 2], w3 = wgt[i + 3];
            unsigned p0 = *(const unsigned*)(neigh + (size_t)s0 * NO + j);
            unsigned p1 = *(const unsigned*)(neigh + (size_t)s1 * NO + j);
            unsigned p2 = *(const unsigned*)(neigh + (size_t)s2 * NO + j);
            unsigned p3 = *(const unsigned*)(neigh + (size_t)s3 * NO + j);
            a0 += bf2f((unsigned short)(p0 & 0xffffu)) * w0 + bf2f((unsigned short)(p2 & 0xffffu)) * w2;
            a1 += bf2f((unsigned short)(p0 >> 16)) * w0 + bf2f((unsigned short)(p2 >> 16)) * w2;
            c0 += bf2f((unsigned short)(p1 & 0xffffu)) * w1 + bf2f((unsigned short)(p3 & 0xffffu)) * w3;
            c1 += bf2f((unsigned short)(p1 >> 16)) * w1 + bf2f((unsigned short)(p3 >> 16)) * w3;
        }
        for (; i < e; ++i) {
            int s0 = col[i];
            float w0 = wgt[i];
            unsigned p0 = *(const unsigned*)(neigh + (size_t)s0 * NO + j);
            a0 += bf2f((unsigned short)(p0 & 0xffffu)) * w0;
            a1 += bf2f((unsigned short)(p0 >> 16)) * w0;
        }
        a0 += c0; a1 += c1;
        acc = a0 * wp[MO + j] + a1 * wp[MO + j + 1];
        const unsigned short* ip = int1 + (size_t)w * MO + lane * 4;
        ushort4 iv = *(const ushort4*)ip;
        const float* wq = wp + lane * 4;
        acc += bf2f(iv.x) * wq[0] + bf2f(iv.y) * wq[1] + bf2f(iv.z) * wq[2] + bf2f(iv.w) * wq[3];
    }
    for (int o = 32; o > 0; o >>= 1) acc += __shfl_down(acc, o, 64);
    if (lane == 0) {
        float pre = (s >= 0) ? (acc + bfb[s]) : 0.0f;
        out[2 * (size_t)N + atom] = pre;
        out[atom] = (float)s;
    }
}

// ---------------- per-batch charge correction ----------------
__global__ void charges_kernel(const float* __restrict__ pre_buf, const int* __restrict__ species,
                               const float* __restrict__ tc, float* __restrict__ out, int N, int A) {
    int b = blockIdx.x;
    int a = threadIdx.x;
    int idx = b * A + a;
    float pre = pre_buf[idx];
    int sp = species[idx];
    bool mask = (sp != -1);
    float v = pre;
    int c = mask ? 1 : 0;
    for (int o = 32; o > 0; o >>= 1) {
        v += __shfl_down(v, o, 64);
        c += __shfl_down(c, o, 64);
    }
    __shared__ float ssum[2];
    __shared__ int scnt[2];
    int wid = threadIdx.x >> 6;
    if ((threadIdx.x & 63) == 0) { ssum[wid] = v; scnt[wid] = c; }
    __syncthreads();
    float total = ssum[0] + ssum[1];
    int nreal = scnt[0] + scnt[1];
    float ch = pre + (tc[b] - total) / (float)max(nreal, 1);
    out[(size_t)N + idx] = mask ? ch : 0.0f;
}

extern "C" void kernel_launch(void* const* d_in, const int* in_sizes, int n_in,
                              void* d_out, int out_size, void* d_ws, size_t ws_size,
                              hipStream_t stream) {
    const int*   species = (const int*)d_in[0];
    const float* aev     = (const float*)d_in[1];
    const int*   ai      = (const int*)d_in[2];
    const float* dist    = (const float*)d_in[3];
    const float* tc      = (const float*)d_in[4];
    const float* Wm0 = (const float*)d_in[5];  const float* bm0 = (const float*)d_in[6];
    const float* Wn0 = (const float*)d_in[7];  const float* bn0 = (const float*)d_in[8];
    const float* Wm1 = (const float*)d_in[9];  const float* bm1 = (const float*)d_in[10];
    const float* Wn1 = (const float*)d_in[11]; const float* bn1 = (const float*)d_in[12];
    const float* Wf  = (const float*)d_in[13]; const float* bf  = (const float*)d_in[14];
    const float* factor    = (const float*)d_in[15];
    const float* prefactor = (const float*)d_in[16];

    const int N   = in_sizes[0];
    const int AEV = in_sizes[1] / N;       // 1008
    const int P   = in_sizes[3];
    const int B   = in_sizes[4];
    const int A   = N / B;

    const int NPAD  = N + 256;
    const int NSCAN = ((NPAD + 1023) / 1024) * 1024;

    float* out = (float*)d_out;

    // ---- workspace layout ----
    char* base = (char*)d_ws;
    size_t o = 0;
    auto take = [&](size_t bytes) -> char* {
        o = (o + 255) & ~(size_t)255;
        char* p = base + o; o += bytes; return p;
    };
    unsigned short* feat1_bf = (unsigned short*)take((size_t)NPAD * FIN * 2);
    unsigned short* int1_bf  = (unsigned short*)take((size_t)NPAD * MO * 2);
    char* region             = take((size_t)NPAD * AEV * 2);
    unsigned short* aev_bf   = (unsigned short*)region;
    unsigned short* neigh_bf = (unsigned short*)region;
    size_t roff = ((size_t)NPAD * NO * 2 + 255) & ~(size_t)255;
    int* rowptr = (int*)(region + roff);  roff += (size_t)(NSCAN + 1) * 4; roff = (roff + 255) & ~(size_t)255;
    int* cursor = (int*)(region + roff);  roff += (size_t)NSCAN * 4;       roff = (roff + 255) & ~(size_t)255;
    int* degree = (int*)(region + roff);  roff += (size_t)NSCAN * 4;       roff = (roff + 255) & ~(size_t)255;
    int* ecol   = (int*)(region + roff);  roff += (size_t)2 * P * 4;       roff = (roff + 255) & ~(size_t)255;
    float* ewgt = (float*)(region + roff);
    unsigned short* Wm0t = (unsigned short*)take((size_t)S_ * MO * AEV * 2);
    unsigned short* Wn0t = (unsigned short*)take((size_t)S_ * NO * MO * 2);
    unsigned short* Wm1t = (unsigned short*)take((size_t)S_ * MO * FIN * 2);
    unsigned short* Wn1t = (unsigned short*)take((size_t)S_ * NO * MO * 2);
    int* perm     = (int*)take((size_t)NPAD * 4);
    int* inv_perm = (int*)take((size_t)N * 4);
    int* cnt      = (int*)take(64);
    const int nb = (N + 255) / 256;
    int* bhist = (int*)take((size_t)nb * 4 * 4);
    int* pbase = (int*)take((size_t)nb * 4 * 4);

    // ---- species sort into padded sorted space ----
    hipMemsetAsync(perm, 0xFF, (size_t)NPAD * 4, stream);
    hipMemsetAsync(inv_perm, 0xFF, (size_t)N * 4, stream);
    species_hist<<<nb, 256, 0, stream>>>(species, bhist, N);
    species_scan<<<1, 64, 0, stream>>>(bhist, cnt, pbase, nb);
    species_fill<<<nb, 256, 0, stream>>>(species, pbase, perm, inv_perm, N);

    // ---- gather-cast aev; weight transposes ----
    cast_gather<<<NPAD, 256, 0, stream>>>(aev, perm, aev_bf, AEV);
    transpose_cast<<<dim3(MO / 32, (AEV + 31) / 32, S_), 256, 0, stream>>>(Wm0, Wm0t, AEV, MO);
    transpose_cast<<<dim3(NO / 32, MO / 32, S_), 256, 0, stream>>>(Wn0, Wn0t, MO, NO);
    transpose_cast<<<dim3(MO / 32, FIN / 32, S_), 256, 0, stream>>>(Wm1, Wm1t, FIN, MO);
    transpose_cast<<<dim3(NO / 32, MO / 32, S_), 256, 0, stream>>>(Wn1, Wn1t, MO, NO);

    const int T64 = NPAD / 64;
    const int T32 = NPAD / 32;

    // ---- pass 0 ----
    mfma_gemm<1008, 256, true><<<dim3(2, T64), 256, 0, stream>>>(
        aev_bf, AEV, Wm0t, bm0, feat1_bf, FIN, cnt);

    hipMemsetAsync(degree, 0, (size_t)NSCAN * 4, stream);
    edge_count<<<(2 * P + 255) / 256, 256, 0, stream>>>(ai, inv_perm, degree, 2 * P);
    scan_rowptr<<<1, 1024, 0, stream>>>(degree, rowptr, cursor, NSCAN);
    edge_fill<<<(2 * P + 255) / 256, 256, 0, stream>>>(ai, dist, factor, prefactor,
                                                       inv_perm, cursor, ecol, ewgt, P);

    mfma_gemm32<256, true><<<dim3(1, T32), 256, 0, stream>>>(
        feat1_bf, FIN, Wn0t, bn0, neigh_bf, NO, cnt);
    gather_rows0<<<NPAD / 4, 256, 0, stream>>>(neigh_bf, rowptr, ecol, ewgt, feat1_bf);

    // ---- pass 1 ----
    mfma_gemm<384, 256, true><<<dim3(2, T64), 256, 0, stream>>>(
        feat1_bf, FIN, Wm1t, bm1, int1_bf, MO, cnt);
    mfma_gemm32<256, true><<<dim3(1, T32), 256, 0, stream>>>(
        int1_bf, MO, Wn1t, bn1, neigh_bf, NO, cnt);

    // ---- fused pass-1 gather + head, then charges ----
    gather_final<<<NPAD / 4, 256, 0, stream>>>(
        neigh_bf, rowptr, ecol, ewgt, int1_bf, perm, species, Wf, bf, out, N);
    charges_kernel<<<B, A, 0, stream>>>(out + 2 * (size_t)N, species, tc, out, N, A);
}